// Round 4
// baseline (194.269 us; speedup 1.0000x reference)
//
#include <hip/hip_runtime.h>
#include <hip/hip_bf16.h>

// Problem constants
#define CIN   128
#define COUT  64
#define HW    16384   // 128*128

typedef __hip_bfloat16 bf16;

// Workspace layout (float offsets)
#define OFF_XT    0u          // bf16[2][64][16384]  xt
#define OFF_PS    1048576u    // bf16[512 blk][64 k][64 o] partial bin sums
#define OFF_PC    2097152u    // f32 [2][64][256]    partial bin counts
#define OFF_MEANS 2129920u    // f32 [2][64][64]
#define OFF_FLG   2138112u    // u32 flags F1,F2,F3 (reuses unused DIAG slot)
#define OFF_INV   2138240u    // f32 [64][64]        inv(cov)
#define OFF_ADJM  2142336u    // f32 [2][64][64]     adj @ means
#define OFF_BNP   2150528u    // f32 [32 oc][16 b*tile] float4 {s0,s1,ss0,ss1}

__device__ __forceinline__ unsigned short f2bfu(float f) {
  union { bf16 h; unsigned short u; } cv; cv.h = __float2bfloat16(f); return cv.u;
}
__device__ __forceinline__ float bf2f(unsigned short u) {
  union { unsigned int i; float f; } cv; cv.i = ((unsigned int)u) << 16; return cv.f;
}

// Relaxed-poll / single-acquire wait (R2 lesson: acquire per poll = invalidate
// storm, 30 GB/s chip-wide; relaxed agent-scope load bypasses stale caches
// without invalidating, acquire ONCE after success).
__device__ __forceinline__ void waitflag(unsigned* f, unsigned target) {
  if (threadIdx.x == 0) {
    while (__hip_atomic_load(f, __ATOMIC_RELAXED, __HIP_MEMORY_SCOPE_AGENT) < target)
      __builtin_amdgcn_s_sleep(32);
    (void)__hip_atomic_load(f, __ATOMIC_ACQUIRE, __HIP_MEMORY_SCOPE_AGENT);
  }
  __syncthreads();
}
__device__ __forceinline__ void postflag(unsigned* f) {
  // callers ensure all block writes retired (syncthreads) before this
  __threadfence();
  if (threadIdx.x == 0)
    __hip_atomic_fetch_add(f, 1u, __ATOMIC_RELEASE, __HIP_MEMORY_SCOPE_AGENT);
}

#define FMA16() do { \
  acc[ 0]=fmaf(xv.x,wv.x,acc[ 0]); acc[ 1]=fmaf(xv.y,wv.x,acc[ 1]); \
  acc[ 2]=fmaf(xv.z,wv.x,acc[ 2]); acc[ 3]=fmaf(xv.w,wv.x,acc[ 3]); \
  acc[ 4]=fmaf(xv.x,wv.y,acc[ 4]); acc[ 5]=fmaf(xv.y,wv.y,acc[ 5]); \
  acc[ 6]=fmaf(xv.z,wv.y,acc[ 6]); acc[ 7]=fmaf(xv.w,wv.y,acc[ 7]); \
  acc[ 8]=fmaf(xv.x,wv.z,acc[ 8]); acc[ 9]=fmaf(xv.y,wv.z,acc[ 9]); \
  acc[10]=fmaf(xv.z,wv.z,acc[10]); acc[11]=fmaf(xv.w,wv.z,acc[11]); \
  acc[12]=fmaf(xv.x,wv.w,acc[12]); acc[13]=fmaf(xv.y,wv.w,acc[13]); \
  acc[14]=fmaf(xv.z,wv.w,acc[14]); acc[15]=fmaf(xv.w,wv.w,acc[15]); \
} while (0)

// ============================================================================
// KA: xt = einsum (bf16 out) + per-block bin partials; block 0 = inv(Wm Wm^T)
// + zero sync flags. Verbatim proven baseline otherwise.
// ============================================================================
__global__ __launch_bounds__(256, 2) void ka_xt_bins_inv(
    const float* __restrict__ x, const int* __restrict__ index,
    const float* __restrict__ Wft, const float* __restrict__ Wm,
    float* __restrict__ ws)
{
  __shared__ __align__(16) float smem[16384];   // 64 KB
  const int blk = blockIdx.x, tid = threadIdx.x;
  if (blk != 0) {
    float* xl = smem;          // [128 c][64 px]
    float* wl = smem + 8192;   // [128 c][64 o]
    const int eb = blk - 1;
    const int b = eb >> 8, ps = eb & 255;
    const float* xg = x + (size_t)b * CIN * HW + ps * 64;
#pragma unroll
    for (int j = 0; j < 8; ++j) {
      const int fj = j * 256 + tid;
      const int c = fj >> 4, q4 = (fj & 15) * 4;
      *(float4*)&xl[c * 64 + q4] = *(const float4*)(xg + (size_t)c * HW + q4);
      *(float4*)&wl[c * 64 + q4] = *(const float4*)(Wft + c * 64 + q4);
    }
    __syncthreads();
    const int px_grp = tid & 15, o_grp = tid >> 4;
    const int px = ps * 64 + px_grp * 4, o0 = o_grp * 4;
    float acc[16];
#pragma unroll
    for (int j = 0; j < 16; ++j) acc[j] = 0.f;
#pragma unroll 8
    for (int c = 0; c < 128; ++c) {
      const float4 xv = *(const float4*)&xl[c * 64 + px_grp * 4];
      const float4 wv = *(const float4*)&wl[c * 64 + o0];
      FMA16();
    }
    unsigned short* xtu = (unsigned short*)(ws + OFF_XT);
#pragma unroll
    for (int oj = 0; oj < 4; ++oj) {
      ushort4 u;
      u.x = f2bfu(acc[oj*4+0]); u.y = f2bfu(acc[oj*4+1]);
      u.z = f2bfu(acc[oj*4+2]); u.w = f2bfu(acc[oj*4+3]);
      *(ushort4*)(xtu + (size_t)(b * 64 + o0 + oj) * HW + px) = u;
    }
    const int4 kv = *(const int4*)(index + b * HW + px);
    const int kk[4] = {kv.x, kv.y, kv.z, kv.w};
    __syncthreads();
    float* bins = smem;
    float* cnt_s = smem + 64 * 68;
    for (int i = tid; i < 64 * 68 + 64; i += 256) smem[i] = 0.f;
    __syncthreads();
#pragma unroll
    for (int pj = 0; pj < 4; ++pj) {
      const int kb = kk[pj] * 68 + o0;
      atomicAdd(&bins[kb    ], acc[ 0 + pj]);
      atomicAdd(&bins[kb + 1], acc[ 4 + pj]);
      atomicAdd(&bins[kb + 2], acc[ 8 + pj]);
      atomicAdd(&bins[kb + 3], acc[12 + pj]);
    }
    if (o_grp == 0) {
#pragma unroll
      for (int pj = 0; pj < 4; ++pj) atomicAdd(&cnt_s[kk[pj]], 1.f);
    }
    __syncthreads();
    unsigned short* pb = (unsigned short*)(ws + OFF_PS) + (size_t)eb * 4096;
    {
      const int k = tid >> 2, ob = (tid & 3) * 16;
#pragma unroll
      for (int q = 0; q < 4; ++q) {
        const float4 v = *(const float4*)&bins[k * 68 + ob + q * 4];
        ushort4 u;
        u.x = f2bfu(v.x); u.y = f2bfu(v.y); u.z = f2bfu(v.z); u.w = f2bfu(v.w);
        *(ushort4*)(pb + k * 64 + ob + q * 4) = u;
      }
    }
    if (tid < 64) ws[OFF_PC + (size_t)(b * 64 + tid) * 256 + ps] = cnt_s[tid];
  } else {
    if (tid == 0) {   // zero KB's sync flags (visible at KB launch via kernel-end flush)
      unsigned* flg = (unsigned*)(ws + OFF_FLG);
      flg[0] = 0u; flg[1] = 0u; flg[2] = 0u;
    }
    // inverse block: blocked Gauss-Jordan, 16 panels of 4 pivots (proven form)
    float* wm = smem;
    float* Rb = smem + 8192;
    float* Cb = smem + 8704;
    for (int e = tid; e < 4096; e += 256) wm[(e >> 6) * 68 + (e & 63)] = Wm[e];
    __syncthreads();
    const int ig = tid >> 4, jg = tid & 15;
    const int i0 = ig << 2, j0 = jg << 2;
    float c4[16];
#pragma unroll
    for (int q = 0; q < 16; ++q) c4[q] = 0.f;
    for (int cq = 0; cq < 64; cq += 4) {
      float4 a[4], bb[4];
#pragma unroll
      for (int ii = 0; ii < 4; ++ii) a[ii]  = *(const float4*)&wm[(i0+ii)*68 + cq];
#pragma unroll
      for (int jj = 0; jj < 4; ++jj) bb[jj] = *(const float4*)&wm[(j0+jj)*68 + cq];
#pragma unroll
      for (int ii = 0; ii < 4; ++ii)
#pragma unroll
        for (int jj = 0; jj < 4; ++jj)
          c4[ii*4+jj] = fmaf(a[ii].x, bb[jj].x, fmaf(a[ii].y, bb[jj].y,
                        fmaf(a[ii].z, bb[jj].z, fmaf(a[ii].w, bb[jj].w, c4[ii*4+jj]))));
    }
    __syncthreads();
    __builtin_amdgcn_s_setprio(3);
    int buf = 0;
#pragma unroll 1   // MUST stay rolled (I$ thrash)
    for (int p = 0; p < 16; ++p) {
      const int P = p << 2;
      float* Rp = Rb + buf * 256;
      float* Cp = Cb + buf * 256;
      if (ig == p) {
#pragma unroll
        for (int r = 0; r < 4; ++r) {
          float4 t; t.x = c4[r*4+0]; t.y = c4[r*4+1]; t.z = c4[r*4+2]; t.w = c4[r*4+3];
          *(float4*)&Rp[r * 64 + j0] = t;
        }
      }
      if (jg == p) {
#pragma unroll
        for (int ii = 0; ii < 4; ++ii) {
          float4 t; t.x = c4[ii*4+0]; t.y = c4[ii*4+1]; t.z = c4[ii*4+2]; t.w = c4[ii*4+3];
          *(float4*)&Cp[(i0 + ii) * 4] = t;
        }
      }
      __syncthreads();
      float dd[16], cc[16], rr[16];
#pragma unroll
      for (int r = 0; r < 4; ++r) *(float4*)&dd[r * 4] = *(const float4*)&Rp[r * 64 + P];
#pragma unroll
      for (int ii = 0; ii < 4; ++ii) *(float4*)&cc[ii * 4] = *(const float4*)&Cp[(i0 + ii) * 4];
#pragma unroll
      for (int r = 0; r < 4; ++r) *(float4*)&rr[r * 4] = *(const float4*)&Rp[r * 64 + j0];
#pragma unroll
      for (int k = 0; k < 4; ++k) {
        const float rp = __builtin_amdgcn_rcpf(dd[k * 4 + k]);
        float ai[4], s[4];
#pragma unroll
        for (int j = 0; j < 4; ++j) s[j] = dd[k * 4 + j];
#pragma unroll
        for (int i = 0; i < 4; ++i) ai[i] = (i == k) ? (rp - 1.0f) : (-dd[i * 4 + k] * rp);
#pragma unroll
        for (int i = 0; i < 4; ++i)
#pragma unroll
          for (int j = 0; j < 4; ++j) dd[i * 4 + j] = fmaf(ai[i], s[j], dd[i * 4 + j]);
#pragma unroll
        for (int i = 0; i < 4; ++i) dd[i * 4 + k] = (i == k) ? rp : ai[i];
      }
      float T[16];
#pragma unroll
      for (int ii = 0; ii < 4; ++ii)
#pragma unroll
        for (int c = 0; c < 4; ++c) {
          float t = cc[ii*4+0] * dd[0*4+c];
          t = fmaf(cc[ii*4+1], dd[1*4+c], t);
          t = fmaf(cc[ii*4+2], dd[2*4+c], t);
          t = fmaf(cc[ii*4+3], dd[3*4+c], t);
          T[ii*4+c] = t;
        }
      if (ig == p && jg == p) {
#pragma unroll
        for (int q = 0; q < 16; ++q) c4[q] = dd[q];
      } else if (ig == p) {
#pragma unroll
        for (int r = 0; r < 4; ++r)
#pragma unroll
          for (int jj = 0; jj < 4; ++jj) {
            float t = dd[r*4+0] * rr[0*4+jj];
            t = fmaf(dd[r*4+1], rr[1*4+jj], t);
            t = fmaf(dd[r*4+2], rr[2*4+jj], t);
            t = fmaf(dd[r*4+3], rr[3*4+jj], t);
            c4[r*4+jj] = t;
          }
      } else if (jg == p) {
#pragma unroll
        for (int q = 0; q < 16; ++q) c4[q] = -T[q];
      } else {
#pragma unroll
        for (int ii = 0; ii < 4; ++ii)
#pragma unroll
          for (int jj = 0; jj < 4; ++jj) {
            float t = c4[ii*4+jj];
            t = fmaf(-T[ii*4+0], rr[0*4+jj], t);
            t = fmaf(-T[ii*4+1], rr[1*4+jj], t);
            t = fmaf(-T[ii*4+2], rr[2*4+jj], t);
            t = fmaf(-T[ii*4+3], rr[3*4+jj], t);
            c4[ii*4+jj] = t;
          }
      }
      buf ^= 1;
    }
    __builtin_amdgcn_s_setprio(0);
#pragma unroll
    for (int ii = 0; ii < 4; ++ii)
#pragma unroll
      for (int jj = 0; jj < 4; ++jj)
        ws[OFF_INV + (size_t)(i0 + ii) * 64 + j0 + jj] = c4[ii*4+jj];
  }
}

// ============================================================================
// KB: means(blk 0..127) -> adj(blk 128..143) -> BN stats(all 512) -> out(all 512)
// chained by relaxed-poll flags. 39.4 KB LDS -> 4 blk/CU -> all 512 co-resident.
// Stats/out inputs preloaded to regs at start (xt complete at KB launch); xt is
// read ONCE for both stats and out.
// ============================================================================
__global__ __launch_bounds__(256) void kb_rest(const int* __restrict__ index,
    const float* __restrict__ gamma, const float* __restrict__ beta,
    float* __restrict__ ws, float* __restrict__ out)
{
  __shared__ __align__(16) float smem[9856];   // 39.4 KB (adj phase is the max)
  unsigned* flg = (unsigned*)(ws + OFF_FLG);
  const int blk = blockIdx.x, tid = threadIdx.x;

  // ---- stats/out identity + register preload (ALL blocks, before any waiting)
  const int b = blk >> 8, oc = (blk >> 3) & 31, tile = blk & 7;
  const int o0s = oc * 2;
  const int lane = tid & 63, w = tid >> 6;
  const unsigned short* xtu = (const unsigned short*)(ws + OFF_XT);
  int4 kvv[2]; ushort4 u0r[2], u1r[2];
#pragma unroll
  for (int q = 0; q < 2; ++q) {
    const int px = tile * 2048 + (w * 2 + q) * 256 + lane * 4;
    kvv[q] = *(const int4*)(index + b * HW + px);
    u0r[q] = *(const ushort4*)(xtu + (size_t)(b * 64 + o0s    ) * HW + px);
    u1r[q] = *(const ushort4*)(xtu + (size_t)(b * 64 + o0s + 1) * HW + px);
  }

  if (blk < 128) {
    // ---------------- means (verified R1/R2 body) ----------------
    const int bb = blk >> 6, k = blk & 63;
    float* red   = smem;           // [16][64]
    float* lds_c = smem + 1024;    // [4]
    const unsigned short* psu = (const unsigned short*)(ws + OFF_PS);
    const int o4 = (tid & 15) * 4, chunk = tid >> 4;
    float s4[4] = {0.f, 0.f, 0.f, 0.f};
#pragma unroll 4
    for (int i = 0; i < 16; ++i) {
      const int slab = chunk * 16 + i;
      const ushort4 u = *(const ushort4*)(psu + (size_t)(bb * 256 + slab) * 4096 + k * 64 + o4);
      s4[0] += bf2f(u.x); s4[1] += bf2f(u.y); s4[2] += bf2f(u.z); s4[3] += bf2f(u.w);
    }
#pragma unroll
    for (int j = 0; j < 4; ++j) red[chunk * 64 + o4 + j] = s4[j];
    float cv = ws[OFF_PC + (size_t)(bb * 64 + k) * 256 + tid];
#pragma unroll
    for (int m = 32; m; m >>= 1) cv += __shfl_xor(cv, m, 64);
    if ((tid & 63) == 0) lds_c[tid >> 6] = cv;
    __syncthreads();
    if (tid < 64) {
      float m_raw = 0.f;
#pragma unroll
      for (int ch = 0; ch < 16; ++ch) m_raw += red[ch * 64 + tid];
      const float cntv = lds_c[0] + lds_c[1] + lds_c[2] + lds_c[3];
      const float denom = cntv + ((cntv == 0.f) ? 1.f : 0.f);
      ws[OFF_MEANS + (size_t)(bb * 64 + k) * 64 + tid] = m_raw / denom;
    }
    __syncthreads();
    postflag(&flg[0]);
  } else if (blk < 144) {
    // ---------------- adj + adjm (verified R1/R2 body) ----------------
    waitflag(&flg[0], 128u);
    const int abl = blk - 128;
    const int bb = abl >> 3, r0 = (abl & 7) << 3;
    float* means_s = smem;            // [64][68]
    float* inv_s   = smem + 4352;     // [64][68]
    float* T_s     = smem + 8704;     // [8][68]
    float* adj_s   = smem + 9248;     // [8][68]
    float* d_s     = smem + 9792;     // [64]
    const float* mg = ws + OFF_MEANS + (size_t)bb * 4096;
    for (int e = tid; e < 4096; e += 256) means_s[(e >> 6) * 68 + (e & 63)] = mg[e];
    for (int e = tid; e < 4096; e += 256) inv_s[(e >> 6) * 68 + (e & 63)] = ws[OFF_INV + e];
    __syncthreads();
    {   // thread = (row j, 16-col strip): T[j][oq..oq+15], d_j partial
      const int j = tid >> 2, oq = (tid & 3) << 4;
      float4 Ta[4];
#pragma unroll
      for (int v = 0; v < 4; ++v) { Ta[v].x = 0.f; Ta[v].y = 0.f; Ta[v].z = 0.f; Ta[v].w = 0.f; }
      for (int c = 0; c < 64; ++c) {
        const float mv = means_s[j * 68 + c];
#pragma unroll
        for (int v = 0; v < 4; ++v) {
          const float4 iv = *(const float4*)&inv_s[c * 68 + oq + v * 4];
          Ta[v].x = fmaf(mv, iv.x, Ta[v].x); Ta[v].y = fmaf(mv, iv.y, Ta[v].y);
          Ta[v].z = fmaf(mv, iv.z, Ta[v].z); Ta[v].w = fmaf(mv, iv.w, Ta[v].w);
        }
      }
      float dp = 0.f;
#pragma unroll
      for (int v = 0; v < 4; ++v) {
        const float4 mvv = *(const float4*)&means_s[j * 68 + oq + v * 4];
        dp = fmaf(Ta[v].x, mvv.x, dp); dp = fmaf(Ta[v].y, mvv.y, dp);
        dp = fmaf(Ta[v].z, mvv.z, dp); dp = fmaf(Ta[v].w, mvv.w, dp);
      }
      dp += __shfl_xor(dp, 1, 64);
      dp += __shfl_xor(dp, 2, 64);
      if ((tid & 3) == 0) d_s[j] = dp;
      if (j >= r0 && j < r0 + 8) {
#pragma unroll
        for (int v = 0; v < 4; ++v) *(float4*)&T_s[(j - r0) * 68 + oq + v * 4] = Ta[v];
      }
    }
    __syncthreads();
    {   // q_ij = d_i + d_j - 2 T_i.m_j ; adj = exp(-sqrt(max(q,1e-12)))
      const int i = tid >> 5, jb = tid & 31;
#pragma unroll
      for (int jj = 0; jj < 2; ++jj) {
        const int jc = jb + (jj << 5);
        float4 p4 = {0.f, 0.f, 0.f, 0.f};
        for (int dq = 0; dq < 64; dq += 4) {
          const float4 tv = *(const float4*)&T_s[i * 68 + dq];
          const float4 mv = *(const float4*)&means_s[jc * 68 + dq];
          p4.x = fmaf(tv.x, mv.x, p4.x); p4.y = fmaf(tv.y, mv.y, p4.y);
          p4.z = fmaf(tv.z, mv.z, p4.z); p4.w = fmaf(tv.w, mv.w, p4.w);
        }
        const float p = (p4.x + p4.y) + (p4.z + p4.w);
        const float q = d_s[r0 + i] + d_s[jc] - 2.f * p;
        adj_s[i * 68 + jc] = __expf(-sqrtf(fmaxf(q, 1e-12f)));
      }
    }
    __syncthreads();
    if (tid < 128) {   // adjm rows
      const int i = tid >> 4, oq4 = (tid & 15) << 2;
      float4 am = {0.f, 0.f, 0.f, 0.f};
      for (int jc = 0; jc < 64; ++jc) {
        const float av = adj_s[i * 68 + jc];
        const float4 mv = *(const float4*)&means_s[jc * 68 + oq4];
        am.x = fmaf(av, mv.x, am.x); am.y = fmaf(av, mv.y, am.y);
        am.z = fmaf(av, mv.z, am.z); am.w = fmaf(av, mv.w, am.w);
      }
      *(float4*)(ws + OFF_ADJM + (size_t)(bb * 64 + r0 + i) * 64 + oq4) = am;
    }
    __syncthreads();
    postflag(&flg[1]);
  }

  // ---------------- all 512: BN partial stats (verified R2 body) ----------------
  waitflag(&flg[1], 16u);
  {
    float* am_s = smem;          // [128]
    float* red4 = smem + 128;    // [4]
    if (tid < 128) am_s[tid] = ws[OFF_ADJM + (size_t)(b * 64 + (tid >> 1)) * 64 + o0s + (tid & 1)];
    if (tid < 4) red4[tid] = 0.f;
    __syncthreads();
    float s0 = 0.f, s1 = 0.f, q0 = 0.f, q1 = 0.f;
#pragma unroll
    for (int q = 0; q < 2; ++q) {
      const int kk[4] = {kvv[q].x, kvv[q].y, kvv[q].z, kvv[q].w};
      const float x0[4] = {bf2f(u0r[q].x), bf2f(u0r[q].y), bf2f(u0r[q].z), bf2f(u0r[q].w)};
      const float x1[4] = {bf2f(u1r[q].x), bf2f(u1r[q].y), bf2f(u1r[q].z), bf2f(u1r[q].w)};
#pragma unroll
      for (int j = 0; j < 4; ++j) {
        const float2 am = *(const float2*)&am_s[kk[j] * 2];
        const float f0 = fmaxf(x0[j] + am.x, 0.f);
        const float f1 = fmaxf(x1[j] + am.y, 0.f);
        s0 += f0; q0 = fmaf(f0, f0, q0);
        s1 += f1; q1 = fmaf(f1, f1, q1);
      }
    }
#pragma unroll
    for (int m = 1; m < 64; m <<= 1) {
      s0 += __shfl_xor(s0, m, 64); s1 += __shfl_xor(s1, m, 64);
      q0 += __shfl_xor(q0, m, 64); q1 += __shfl_xor(q1, m, 64);
    }
    if (lane == 0) {
      atomicAdd(&red4[0], s0); atomicAdd(&red4[1], s1);
      atomicAdd(&red4[2], q0); atomicAdd(&red4[3], q1);
    }
    __syncthreads();
    if (tid == 0) {
      float4 v; v.x = red4[0]; v.y = red4[1]; v.z = red4[2]; v.w = red4[3];
      *(float4*)(ws + OFF_BNP + (size_t)(oc * 16 + b * 8 + tile) * 4) = v;
    }
    __syncthreads();
    postflag(&flg[2]);
  }

  // ---------------- all 512: BN final + out (K4 body; am_s persists in LDS,
  //                  xt/index reused from regs) ----------------
  waitflag(&flg[2], 512u);
  {
    float* am_s  = smem;                        // persists from stats phase
    float4* tmp  = (float4*)(smem + 128);       // [16]
    float* sc_s  = smem + 192;
    float* sh_s  = smem + 194;
    if (tid < 16) tmp[tid] = *(const float4*)(ws + OFF_BNP + (size_t)(oc * 16 + tid) * 4);
    if (tid < 2) {   // same wave as tmp writers: per-wave LDS ordering suffices
      float s = 0.f, qq = 0.f;
#pragma unroll
      for (int i = 0; i < 16; ++i) {
        const float4 v = tmp[i];
        s  += (tid == 0) ? v.x : v.y;
        qq += (tid == 0) ? v.z : v.w;
      }
      const float mean = s * (1.f / 32768.f);
      const float var  = qq * (1.f / 32768.f) - mean * mean;
      const float sc = gamma[o0s + tid] * rsqrtf(var + 1e-5f);
      sc_s[tid] = sc;
      sh_s[tid] = fmaf(-mean, sc, beta[o0s + tid]);
    }
    __syncthreads();
    const float c0 = sc_s[0], c1 = sc_s[1], h0 = sh_s[0], h1 = sh_s[1];
#pragma unroll
    for (int q = 0; q < 2; ++q) {
      const int px = tile * 2048 + (w * 2 + q) * 256 + lane * 4;
      const int kk[4] = {kvv[q].x, kvv[q].y, kvv[q].z, kvv[q].w};
      const float x0[4] = {bf2f(u0r[q].x), bf2f(u0r[q].y), bf2f(u0r[q].z), bf2f(u0r[q].w)};
      const float x1[4] = {bf2f(u1r[q].x), bf2f(u1r[q].y), bf2f(u1r[q].z), bf2f(u1r[q].w)};
      float4 o4a, o4b;
      float* oa = (float*)&o4a; float* ob = (float*)&o4b;
#pragma unroll
      for (int j = 0; j < 4; ++j) {
        const float2 am = *(const float2*)&am_s[kk[j] * 2];
        oa[j] = fmaf(fmaxf(x0[j] + am.x, 0.f), c0, h0);
        ob[j] = fmaf(fmaxf(x1[j] + am.y, 0.f), c1, h1);
      }
      *(float4*)(out + (size_t)(b * 64 + o0s    ) * HW + px) = o4a;
      *(float4*)(out + (size_t)(b * 64 + o0s + 1) * HW + px) = o4b;
    }
  }
}

extern "C" void kernel_launch(void* const* d_in, const int* in_sizes, int n_in,
                              void* d_out, int out_size, void* d_ws, size_t ws_size,
                              hipStream_t stream) {
  const float* x     = (const float*)d_in[0];
  const int*   index = (const int*)d_in[1];
  const float* Wft   = (const float*)d_in[2];
  const float* Wm    = (const float*)d_in[3];
  const float* gamma = (const float*)d_in[4];
  const float* beta  = (const float*)d_in[5];
  float* ws  = (float*)d_ws;
  float* out = (float*)d_out;

  ka_xt_bins_inv<<<513, 256, 0, stream>>>(x, index, Wft, Wm, ws);
  kb_rest<<<512, 256, 0, stream>>>(index, gamma, beta, ws, out);
}

// Round 5
// 172.651 us; speedup vs baseline: 1.1252x; 1.1252x over previous
//
#include <hip/hip_runtime.h>
#include <hip/hip_bf16.h>

// Problem constants
#define CIN   128
#define COUT  64
#define HW    16384   // 128*128

typedef __hip_bfloat16 bf16;

// Workspace layout (float offsets)
#define OFF_XT    0u          // bf16[2][64][16384]  xt
#define OFF_PS    1048576u    // bf16[512 blk][64 k][64 o] partial bin sums
#define OFF_PC    2097152u    // f32 [2][64][256]    partial bin counts
#define OFF_MEANS 2129920u    // f32 [2][64][64]
#define OFF_FLG   2138112u    // u32 flags: [0]=means,[1]=adj,[2..33]=per-oc stats
#define OFF_INV   2138240u    // f32 [64][64]        inv(cov)
#define OFF_ADJM  2142336u    // f32 [2][64][64]     adj @ means
#define OFF_BNP   2150528u    // f32 [32 oc][16 b*tile] float4 {s0,s1,ss0,ss1}

__device__ __forceinline__ unsigned short f2bfu(float f) {
  union { bf16 h; unsigned short u; } cv; cv.h = __float2bfloat16(f); return cv.u;
}
__device__ __forceinline__ float bf2f(unsigned short u) {
  union { unsigned int i; float f; } cv; cv.i = ((unsigned int)u) << 16; return cv.f;
}

// Poll primitive v3 (R2 lesson: acquire-per-poll = invalidate storm; R4 lesson:
// relaxed LOAD hits stale local L2 until eviction, ~30us limbo per phase).
// atomicAdd(f,0) is an RMW: executes at the device-coherent point -> always
// FRESH, and invalidates nothing. One acquire only after success.
__device__ __forceinline__ void waitflag(unsigned* f, unsigned target) {
  if (threadIdx.x == 0) {
    while (__hip_atomic_fetch_add(f, 0u, __ATOMIC_RELAXED, __HIP_MEMORY_SCOPE_AGENT) < target)
      __builtin_amdgcn_s_sleep(64);
    (void)__hip_atomic_load(f, __ATOMIC_ACQUIRE, __HIP_MEMORY_SCOPE_AGENT);
  }
  __syncthreads();
}
// Call AFTER __syncthreads() (barrier drains all waves' stores to local L2);
// tid0's threadfence writes back L2, release-add publishes. One fence per block.
__device__ __forceinline__ void postflag(unsigned* f) {
  __threadfence();
  __hip_atomic_fetch_add(f, 1u, __ATOMIC_RELEASE, __HIP_MEMORY_SCOPE_AGENT);
}

#define FMA16() do { \
  acc[ 0]=fmaf(xv.x,wv.x,acc[ 0]); acc[ 1]=fmaf(xv.y,wv.x,acc[ 1]); \
  acc[ 2]=fmaf(xv.z,wv.x,acc[ 2]); acc[ 3]=fmaf(xv.w,wv.x,acc[ 3]); \
  acc[ 4]=fmaf(xv.x,wv.y,acc[ 4]); acc[ 5]=fmaf(xv.y,wv.y,acc[ 5]); \
  acc[ 6]=fmaf(xv.z,wv.y,acc[ 6]); acc[ 7]=fmaf(xv.w,wv.y,acc[ 7]); \
  acc[ 8]=fmaf(xv.x,wv.z,acc[ 8]); acc[ 9]=fmaf(xv.y,wv.z,acc[ 9]); \
  acc[10]=fmaf(xv.z,wv.z,acc[10]); acc[11]=fmaf(xv.w,wv.z,acc[11]); \
  acc[12]=fmaf(xv.x,wv.w,acc[12]); acc[13]=fmaf(xv.y,wv.w,acc[13]); \
  acc[14]=fmaf(xv.z,wv.w,acc[14]); acc[15]=fmaf(xv.w,wv.w,acc[15]); \
} while (0)

// ============================================================================
// KA: xt = einsum (bf16 out) + per-block bin partials; block 0 = inv(Wm Wm^T)
// + zero the 34 sync words. Verbatim proven baseline otherwise.
// ============================================================================
__global__ __launch_bounds__(256, 2) void ka_xt_bins_inv(
    const float* __restrict__ x, const int* __restrict__ index,
    const float* __restrict__ Wft, const float* __restrict__ Wm,
    float* __restrict__ ws)
{
  __shared__ __align__(16) float smem[16384];   // 64 KB
  const int blk = blockIdx.x, tid = threadIdx.x;
  if (blk != 0) {
    float* xl = smem;          // [128 c][64 px]
    float* wl = smem + 8192;   // [128 c][64 o]
    const int eb = blk - 1;
    const int b = eb >> 8, ps = eb & 255;
    const float* xg = x + (size_t)b * CIN * HW + ps * 64;
#pragma unroll
    for (int j = 0; j < 8; ++j) {
      const int fj = j * 256 + tid;
      const int c = fj >> 4, q4 = (fj & 15) * 4;
      *(float4*)&xl[c * 64 + q4] = *(const float4*)(xg + (size_t)c * HW + q4);
      *(float4*)&wl[c * 64 + q4] = *(const float4*)(Wft + c * 64 + q4);
    }
    __syncthreads();
    const int px_grp = tid & 15, o_grp = tid >> 4;
    const int px = ps * 64 + px_grp * 4, o0 = o_grp * 4;
    float acc[16];
#pragma unroll
    for (int j = 0; j < 16; ++j) acc[j] = 0.f;
#pragma unroll 8
    for (int c = 0; c < 128; ++c) {
      const float4 xv = *(const float4*)&xl[c * 64 + px_grp * 4];
      const float4 wv = *(const float4*)&wl[c * 64 + o0];
      FMA16();
    }
    unsigned short* xtu = (unsigned short*)(ws + OFF_XT);
#pragma unroll
    for (int oj = 0; oj < 4; ++oj) {
      ushort4 u;
      u.x = f2bfu(acc[oj*4+0]); u.y = f2bfu(acc[oj*4+1]);
      u.z = f2bfu(acc[oj*4+2]); u.w = f2bfu(acc[oj*4+3]);
      *(ushort4*)(xtu + (size_t)(b * 64 + o0 + oj) * HW + px) = u;
    }
    const int4 kv = *(const int4*)(index + b * HW + px);
    const int kk[4] = {kv.x, kv.y, kv.z, kv.w};
    __syncthreads();
    float* bins = smem;
    float* cnt_s = smem + 64 * 68;
    for (int i = tid; i < 64 * 68 + 64; i += 256) smem[i] = 0.f;
    __syncthreads();
#pragma unroll
    for (int pj = 0; pj < 4; ++pj) {
      const int kb = kk[pj] * 68 + o0;
      atomicAdd(&bins[kb    ], acc[ 0 + pj]);
      atomicAdd(&bins[kb + 1], acc[ 4 + pj]);
      atomicAdd(&bins[kb + 2], acc[ 8 + pj]);
      atomicAdd(&bins[kb + 3], acc[12 + pj]);
    }
    if (o_grp == 0) {
#pragma unroll
      for (int pj = 0; pj < 4; ++pj) atomicAdd(&cnt_s[kk[pj]], 1.f);
    }
    __syncthreads();
    unsigned short* pb = (unsigned short*)(ws + OFF_PS) + (size_t)eb * 4096;
    {
      const int k = tid >> 2, ob = (tid & 3) * 16;
#pragma unroll
      for (int q = 0; q < 4; ++q) {
        const float4 v = *(const float4*)&bins[k * 68 + ob + q * 4];
        ushort4 u;
        u.x = f2bfu(v.x); u.y = f2bfu(v.y); u.z = f2bfu(v.z); u.w = f2bfu(v.w);
        *(ushort4*)(pb + k * 64 + ob + q * 4) = u;
      }
    }
    if (tid < 64) ws[OFF_PC + (size_t)(b * 64 + tid) * 256 + ps] = cnt_s[tid];
  } else {
    if (tid < 34) ((unsigned*)(ws + OFF_FLG))[tid] = 0u;   // zero sync words
    // inverse block: blocked Gauss-Jordan, 16 panels of 4 pivots (proven form)
    float* wm = smem;
    float* Rb = smem + 8192;
    float* Cb = smem + 8704;
    for (int e = tid; e < 4096; e += 256) wm[(e >> 6) * 68 + (e & 63)] = Wm[e];
    __syncthreads();
    const int ig = tid >> 4, jg = tid & 15;
    const int i0 = ig << 2, j0 = jg << 2;
    float c4[16];
#pragma unroll
    for (int q = 0; q < 16; ++q) c4[q] = 0.f;
    for (int cq = 0; cq < 64; cq += 4) {
      float4 a[4], bb[4];
#pragma unroll
      for (int ii = 0; ii < 4; ++ii) a[ii]  = *(const float4*)&wm[(i0+ii)*68 + cq];
#pragma unroll
      for (int jj = 0; jj < 4; ++jj) bb[jj] = *(const float4*)&wm[(j0+jj)*68 + cq];
#pragma unroll
      for (int ii = 0; ii < 4; ++ii)
#pragma unroll
        for (int jj = 0; jj < 4; ++jj)
          c4[ii*4+jj] = fmaf(a[ii].x, bb[jj].x, fmaf(a[ii].y, bb[jj].y,
                        fmaf(a[ii].z, bb[jj].z, fmaf(a[ii].w, bb[jj].w, c4[ii*4+jj]))));
    }
    __syncthreads();
    __builtin_amdgcn_s_setprio(3);
    int buf = 0;
#pragma unroll 1   // MUST stay rolled (I$ thrash)
    for (int p = 0; p < 16; ++p) {
      const int P = p << 2;
      float* Rp = Rb + buf * 256;
      float* Cp = Cb + buf * 256;
      if (ig == p) {
#pragma unroll
        for (int r = 0; r < 4; ++r) {
          float4 t; t.x = c4[r*4+0]; t.y = c4[r*4+1]; t.z = c4[r*4+2]; t.w = c4[r*4+3];
          *(float4*)&Rp[r * 64 + j0] = t;
        }
      }
      if (jg == p) {
#pragma unroll
        for (int ii = 0; ii < 4; ++ii) {
          float4 t; t.x = c4[ii*4+0]; t.y = c4[ii*4+1]; t.z = c4[ii*4+2]; t.w = c4[ii*4+3];
          *(float4*)&Cp[(i0 + ii) * 4] = t;
        }
      }
      __syncthreads();
      float dd[16], cc[16], rr[16];
#pragma unroll
      for (int r = 0; r < 4; ++r) *(float4*)&dd[r * 4] = *(const float4*)&Rp[r * 64 + P];
#pragma unroll
      for (int ii = 0; ii < 4; ++ii) *(float4*)&cc[ii * 4] = *(const float4*)&Cp[(i0 + ii) * 4];
#pragma unroll
      for (int r = 0; r < 4; ++r) *(float4*)&rr[r * 4] = *(const float4*)&Rp[r * 64 + j0];
#pragma unroll
      for (int k = 0; k < 4; ++k) {
        const float rp = __builtin_amdgcn_rcpf(dd[k * 4 + k]);
        float ai[4], s[4];
#pragma unroll
        for (int j = 0; j < 4; ++j) s[j] = dd[k * 4 + j];
#pragma unroll
        for (int i = 0; i < 4; ++i) ai[i] = (i == k) ? (rp - 1.0f) : (-dd[i * 4 + k] * rp);
#pragma unroll
        for (int i = 0; i < 4; ++i)
#pragma unroll
          for (int j = 0; j < 4; ++j) dd[i * 4 + j] = fmaf(ai[i], s[j], dd[i * 4 + j]);
#pragma unroll
        for (int i = 0; i < 4; ++i) dd[i * 4 + k] = (i == k) ? rp : ai[i];
      }
      float T[16];
#pragma unroll
      for (int ii = 0; ii < 4; ++ii)
#pragma unroll
        for (int c = 0; c < 4; ++c) {
          float t = cc[ii*4+0] * dd[0*4+c];
          t = fmaf(cc[ii*4+1], dd[1*4+c], t);
          t = fmaf(cc[ii*4+2], dd[2*4+c], t);
          t = fmaf(cc[ii*4+3], dd[3*4+c], t);
          T[ii*4+c] = t;
        }
      if (ig == p && jg == p) {
#pragma unroll
        for (int q = 0; q < 16; ++q) c4[q] = dd[q];
      } else if (ig == p) {
#pragma unroll
        for (int r = 0; r < 4; ++r)
#pragma unroll
          for (int jj = 0; jj < 4; ++jj) {
            float t = dd[r*4+0] * rr[0*4+jj];
            t = fmaf(dd[r*4+1], rr[1*4+jj], t);
            t = fmaf(dd[r*4+2], rr[2*4+jj], t);
            t = fmaf(dd[r*4+3], rr[3*4+jj], t);
            c4[r*4+jj] = t;
          }
      } else if (jg == p) {
#pragma unroll
        for (int q = 0; q < 16; ++q) c4[q] = -T[q];
      } else {
#pragma unroll
        for (int ii = 0; ii < 4; ++ii)
#pragma unroll
          for (int jj = 0; jj < 4; ++jj) {
            float t = c4[ii*4+jj];
            t = fmaf(-T[ii*4+0], rr[0*4+jj], t);
            t = fmaf(-T[ii*4+1], rr[1*4+jj], t);
            t = fmaf(-T[ii*4+2], rr[2*4+jj], t);
            t = fmaf(-T[ii*4+3], rr[3*4+jj], t);
            c4[ii*4+jj] = t;
          }
      }
      buf ^= 1;
    }
    __builtin_amdgcn_s_setprio(0);
#pragma unroll
    for (int ii = 0; ii < 4; ++ii)
#pragma unroll
      for (int jj = 0; jj < 4; ++jj)
        ws[OFF_INV + (size_t)(i0 + ii) * 64 + j0 + jj] = c4[ii*4+jj];
  }
}

// ============================================================================
// KB v2: means(0..127) -> adj(128..143) -> BN stats(all) -> out(all), chained
// by RMW-poll flags (fresh + non-invalidating). Final barrier is per-oc (32
// counters, 16 producers each) instead of grid-wide. 39.4 KB LDS -> 4 blk/CU
// -> all 512 co-resident, deadlock-free.
// ============================================================================
__global__ __launch_bounds__(256) void kb_rest(const int* __restrict__ index,
    const float* __restrict__ gamma, const float* __restrict__ beta,
    float* __restrict__ ws, float* __restrict__ out)
{
  __shared__ __align__(16) float smem[9856];   // 39.4 KB (adj phase is the max)
  unsigned* flg = (unsigned*)(ws + OFF_FLG);
  unsigned* occ = flg + 2;                      // [32] per-oc counters
  const int blk = blockIdx.x, tid = threadIdx.x;

  // ---- stats/out identity + register preload (ALL blocks, before any waiting)
  const int b = blk >> 8, oc = (blk >> 3) & 31, tile = blk & 7;
  const int o0s = oc * 2;
  const int lane = tid & 63, w = tid >> 6;
  const unsigned short* xtu = (const unsigned short*)(ws + OFF_XT);
  int4 kvv[2]; ushort4 u0r[2], u1r[2];
#pragma unroll
  for (int q = 0; q < 2; ++q) {
    const int px = tile * 2048 + (w * 2 + q) * 256 + lane * 4;
    kvv[q] = *(const int4*)(index + b * HW + px);
    u0r[q] = *(const ushort4*)(xtu + (size_t)(b * 64 + o0s    ) * HW + px);
    u1r[q] = *(const ushort4*)(xtu + (size_t)(b * 64 + o0s + 1) * HW + px);
  }

  if (blk < 128) {
    // ---------------- means (verified R1/R2/R4 body) ----------------
    const int bb = blk >> 6, k = blk & 63;
    float* red   = smem;           // [16][64]
    float* lds_c = smem + 1024;    // [4]
    const unsigned short* psu = (const unsigned short*)(ws + OFF_PS);
    const int o4 = (tid & 15) * 4, chunk = tid >> 4;
    float s4[4] = {0.f, 0.f, 0.f, 0.f};
#pragma unroll 4
    for (int i = 0; i < 16; ++i) {
      const int slab = chunk * 16 + i;
      const ushort4 u = *(const ushort4*)(psu + (size_t)(bb * 256 + slab) * 4096 + k * 64 + o4);
      s4[0] += bf2f(u.x); s4[1] += bf2f(u.y); s4[2] += bf2f(u.z); s4[3] += bf2f(u.w);
    }
#pragma unroll
    for (int j = 0; j < 4; ++j) red[chunk * 64 + o4 + j] = s4[j];
    float cv = ws[OFF_PC + (size_t)(bb * 64 + k) * 256 + tid];
#pragma unroll
    for (int m = 32; m; m >>= 1) cv += __shfl_xor(cv, m, 64);
    if ((tid & 63) == 0) lds_c[tid >> 6] = cv;
    __syncthreads();
    if (tid < 64) {
      float m_raw = 0.f;
#pragma unroll
      for (int ch = 0; ch < 16; ++ch) m_raw += red[ch * 64 + tid];
      const float cntv = lds_c[0] + lds_c[1] + lds_c[2] + lds_c[3];
      const float denom = cntv + ((cntv == 0.f) ? 1.f : 0.f);
      ws[OFF_MEANS + (size_t)(bb * 64 + k) * 64 + tid] = m_raw / denom;
    }
    __syncthreads();
    if (tid == 0) postflag(&flg[0]);
  } else if (blk < 144) {
    // ---------------- adj + adjm (verified R1/R2/R4 body) ----------------
    waitflag(&flg[0], 128u);
    const int abl = blk - 128;
    const int bb = abl >> 3, r0 = (abl & 7) << 3;
    float* means_s = smem;            // [64][68]
    float* inv_s   = smem + 4352;     // [64][68]
    float* T_s     = smem + 8704;     // [8][68]
    float* adj_s   = smem + 9248;     // [8][68]
    float* d_s     = smem + 9792;     // [64]
    const float* mg = ws + OFF_MEANS + (size_t)bb * 4096;
    for (int e = tid; e < 4096; e += 256) means_s[(e >> 6) * 68 + (e & 63)] = mg[e];
    for (int e = tid; e < 4096; e += 256) inv_s[(e >> 6) * 68 + (e & 63)] = ws[OFF_INV + e];
    __syncthreads();
    {   // thread = (row j, 16-col strip): T[j][oq..oq+15], d_j partial
      const int j = tid >> 2, oq = (tid & 3) << 4;
      float4 Ta[4];
#pragma unroll
      for (int v = 0; v < 4; ++v) { Ta[v].x = 0.f; Ta[v].y = 0.f; Ta[v].z = 0.f; Ta[v].w = 0.f; }
      for (int c = 0; c < 64; ++c) {
        const float mv = means_s[j * 68 + c];
#pragma unroll
        for (int v = 0; v < 4; ++v) {
          const float4 iv = *(const float4*)&inv_s[c * 68 + oq + v * 4];
          Ta[v].x = fmaf(mv, iv.x, Ta[v].x); Ta[v].y = fmaf(mv, iv.y, Ta[v].y);
          Ta[v].z = fmaf(mv, iv.z, Ta[v].z); Ta[v].w = fmaf(mv, iv.w, Ta[v].w);
        }
      }
      float dp = 0.f;
#pragma unroll
      for (int v = 0; v < 4; ++v) {
        const float4 mvv = *(const float4*)&means_s[j * 68 + oq + v * 4];
        dp = fmaf(Ta[v].x, mvv.x, dp); dp = fmaf(Ta[v].y, mvv.y, dp);
        dp = fmaf(Ta[v].z, mvv.z, dp); dp = fmaf(Ta[v].w, mvv.w, dp);
      }
      dp += __shfl_xor(dp, 1, 64);
      dp += __shfl_xor(dp, 2, 64);
      if ((tid & 3) == 0) d_s[j] = dp;
      if (j >= r0 && j < r0 + 8) {
#pragma unroll
        for (int v = 0; v < 4; ++v) *(float4*)&T_s[(j - r0) * 68 + oq + v * 4] = Ta[v];
      }
    }
    __syncthreads();
    {   // q_ij = d_i + d_j - 2 T_i.m_j ; adj = exp(-sqrt(max(q,1e-12)))
      const int i = tid >> 5, jb = tid & 31;
#pragma unroll
      for (int jj = 0; jj < 2; ++jj) {
        const int jc = jb + (jj << 5);
        float4 p4 = {0.f, 0.f, 0.f, 0.f};
        for (int dq = 0; dq < 64; dq += 4) {
          const float4 tv = *(const float4*)&T_s[i * 68 + dq];
          const float4 mv = *(const float4*)&means_s[jc * 68 + dq];
          p4.x = fmaf(tv.x, mv.x, p4.x); p4.y = fmaf(tv.y, mv.y, p4.y);
          p4.z = fmaf(tv.z, mv.z, p4.z); p4.w = fmaf(tv.w, mv.w, p4.w);
        }
        const float p = (p4.x + p4.y) + (p4.z + p4.w);
        const float q = d_s[r0 + i] + d_s[jc] - 2.f * p;
        adj_s[i * 68 + jc] = __expf(-sqrtf(fmaxf(q, 1e-12f)));
      }
    }
    __syncthreads();
    if (tid < 128) {   // adjm rows
      const int i = tid >> 4, oq4 = (tid & 15) << 2;
      float4 am = {0.f, 0.f, 0.f, 0.f};
      for (int jc = 0; jc < 64; ++jc) {
        const float av = adj_s[i * 68 + jc];
        const float4 mv = *(const float4*)&means_s[jc * 68 + oq4];
        am.x = fmaf(av, mv.x, am.x); am.y = fmaf(av, mv.y, am.y);
        am.z = fmaf(av, mv.z, am.z); am.w = fmaf(av, mv.w, am.w);
      }
      *(float4*)(ws + OFF_ADJM + (size_t)(bb * 64 + r0 + i) * 64 + oq4) = am;
    }
    __syncthreads();
    if (tid == 0) postflag(&flg[1]);
  }

  // ---------------- all 512: BN partial stats (verified R2/R4 body) ----------------
  waitflag(&flg[1], 16u);
  {
    float* am_s = smem;          // [128]
    float* red4 = smem + 128;    // [4]
    if (tid < 128) am_s[tid] = ws[OFF_ADJM + (size_t)(b * 64 + (tid >> 1)) * 64 + o0s + (tid & 1)];
    if (tid < 4) red4[tid] = 0.f;
    __syncthreads();
    float s0 = 0.f, s1 = 0.f, q0 = 0.f, q1 = 0.f;
#pragma unroll
    for (int q = 0; q < 2; ++q) {
      const int kk[4] = {kvv[q].x, kvv[q].y, kvv[q].z, kvv[q].w};
      const float x0[4] = {bf2f(u0r[q].x), bf2f(u0r[q].y), bf2f(u0r[q].z), bf2f(u0r[q].w)};
      const float x1[4] = {bf2f(u1r[q].x), bf2f(u1r[q].y), bf2f(u1r[q].z), bf2f(u1r[q].w)};
#pragma unroll
      for (int j = 0; j < 4; ++j) {
        const float2 am = *(const float2*)&am_s[kk[j] * 2];
        const float f0 = fmaxf(x0[j] + am.x, 0.f);
        const float f1 = fmaxf(x1[j] + am.y, 0.f);
        s0 += f0; q0 = fmaf(f0, f0, q0);
        s1 += f1; q1 = fmaf(f1, f1, q1);
      }
    }
#pragma unroll
    for (int m = 1; m < 64; m <<= 1) {
      s0 += __shfl_xor(s0, m, 64); s1 += __shfl_xor(s1, m, 64);
      q0 += __shfl_xor(q0, m, 64); q1 += __shfl_xor(q1, m, 64);
    }
    if (lane == 0) {
      atomicAdd(&red4[0], s0); atomicAdd(&red4[1], s1);
      atomicAdd(&red4[2], q0); atomicAdd(&red4[3], q1);
    }
    __syncthreads();
    if (tid == 0) {
      float4 v; v.x = red4[0]; v.y = red4[1]; v.z = red4[2]; v.w = red4[3];
      *(float4*)(ws + OFF_BNP + (size_t)(oc * 16 + b * 8 + tile) * 4) = v;
      postflag(&occ[oc]);   // same thread as the store: program order + fence
    }
  }

  // ---------------- per-oc wait, then BN final + out (regs reused) ----------------
  waitflag(&occ[oc], 16u);
  {
    float* am_s  = smem;                        // persists from stats phase
    float4* tmp  = (float4*)(smem + 128);       // [16]
    float* sc_s  = smem + 192;
    float* sh_s  = smem + 194;
    if (tid < 16) tmp[tid] = *(const float4*)(ws + OFF_BNP + (size_t)(oc * 16 + tid) * 4);
    if (tid < 2) {   // same wave as tmp writers: per-wave LDS ordering suffices
      float s = 0.f, qq = 0.f;
#pragma unroll
      for (int i = 0; i < 16; ++i) {
        const float4 v = tmp[i];
        s  += (tid == 0) ? v.x : v.y;
        qq += (tid == 0) ? v.z : v.w;
      }
      const float mean = s * (1.f / 32768.f);
      const float var  = qq * (1.f / 32768.f) - mean * mean;
      const float sc = gamma[o0s + tid] * rsqrtf(var + 1e-5f);
      sc_s[tid] = sc;
      sh_s[tid] = fmaf(-mean, sc, beta[o0s + tid]);
    }
    __syncthreads();
    const float c0 = sc_s[0], c1 = sc_s[1], h0 = sh_s[0], h1 = sh_s[1];
#pragma unroll
    for (int q = 0; q < 2; ++q) {
      const int px = tile * 2048 + (w * 2 + q) * 256 + lane * 4;
      const int kk[4] = {kvv[q].x, kvv[q].y, kvv[q].z, kvv[q].w};
      const float x0[4] = {bf2f(u0r[q].x), bf2f(u0r[q].y), bf2f(u0r[q].z), bf2f(u0r[q].w)};
      const float x1[4] = {bf2f(u1r[q].x), bf2f(u1r[q].y), bf2f(u1r[q].z), bf2f(u1r[q].w)};
      float4 o4a, o4b;
      float* oa = (float*)&o4a; float* ob = (float*)&o4b;
#pragma unroll
      for (int j = 0; j < 4; ++j) {
        const float2 am = *(const float2*)&am_s[kk[j] * 2];
        oa[j] = fmaf(fmaxf(x0[j] + am.x, 0.f), c0, h0);
        ob[j] = fmaf(fmaxf(x1[j] + am.y, 0.f), c1, h1);
      }
      *(float4*)(out + (size_t)(b * 64 + o0s    ) * HW + px) = o4a;
      *(float4*)(out + (size_t)(b * 64 + o0s + 1) * HW + px) = o4b;
    }
  }
}

extern "C" void kernel_launch(void* const* d_in, const int* in_sizes, int n_in,
                              void* d_out, int out_size, void* d_ws, size_t ws_size,
                              hipStream_t stream) {
  const float* x     = (const float*)d_in[0];
  const int*   index = (const int*)d_in[1];
  const float* Wft   = (const float*)d_in[2];
  const float* Wm    = (const float*)d_in[3];
  const float* gamma = (const float*)d_in[4];
  const float* beta  = (const float*)d_in[5];
  float* ws  = (float*)d_ws;
  float* out = (float*)d_out;

  ka_xt_bins_inv<<<513, 256, 0, stream>>>(x, index, Wft, Wm, ws);
  kb_rest<<<512, 256, 0, stream>>>(index, gamma, beta, ws, out);
}

// Round 6
// 143.818 us; speedup vs baseline: 1.3508x; 1.2005x over previous
//
#include <hip/hip_runtime.h>
#include <hip/hip_bf16.h>

// Problem constants
#define CIN   128
#define COUT  64
#define HW    16384   // 128*128

typedef __hip_bfloat16 bf16;

// Workspace layout (float offsets)
#define OFF_XT    0u          // bf16[2][64][16384]  xt
#define OFF_PS    1048576u    // bf16[512 blk][64 k][64 o] partial bin sums
#define OFF_PC    2097152u    // f32 [2][64][256]    partial bin counts
#define OFF_MEANS 2129920u    // f32 [2][64][64]
#define OFF_FLG   2138112u    // u32 rank counter (old DIAG slot)
#define OFF_INV   2138240u    // f32 [64][64]        inv(cov)
#define OFF_ADJM  2142336u    // f32 [2][64][64]     adj @ means
#define OFF_BNP   2150528u    // f32 [32 oc][16 b*tile] float4 {s0,s1,ss0,ss1}

__device__ __forceinline__ unsigned short f2bfu(float f) {
  union { bf16 h; unsigned short u; } cv; cv.h = __float2bfloat16(f); return cv.u;
}
__device__ __forceinline__ float bf2f(unsigned short u) {
  union { unsigned int i; float f; } cv; cv.i = ((unsigned int)u) << 16; return cv.f;
}

#define FMA16() do { \
  acc[ 0]=fmaf(xv.x,wv.x,acc[ 0]); acc[ 1]=fmaf(xv.y,wv.x,acc[ 1]); \
  acc[ 2]=fmaf(xv.z,wv.x,acc[ 2]); acc[ 3]=fmaf(xv.w,wv.x,acc[ 3]); \
  acc[ 4]=fmaf(xv.x,wv.y,acc[ 4]); acc[ 5]=fmaf(xv.y,wv.y,acc[ 5]); \
  acc[ 6]=fmaf(xv.z,wv.y,acc[ 6]); acc[ 7]=fmaf(xv.w,wv.y,acc[ 7]); \
  acc[ 8]=fmaf(xv.x,wv.z,acc[ 8]); acc[ 9]=fmaf(xv.y,wv.z,acc[ 9]); \
  acc[10]=fmaf(xv.z,wv.z,acc[10]); acc[11]=fmaf(xv.w,wv.z,acc[11]); \
  acc[12]=fmaf(xv.x,wv.w,acc[12]); acc[13]=fmaf(xv.y,wv.w,acc[13]); \
  acc[14]=fmaf(xv.z,wv.w,acc[14]); acc[15]=fmaf(xv.w,wv.w,acc[15]); \
} while (0)

// ============================================================================
// K1: xt = einsum (bf16 out) + per-block bin partials; block 0 = inv(Wm Wm^T)
// + zero the rank counter (consumed by K15' next launch — boundary publishes).
// Verbatim proven 121us baseline otherwise.
// ============================================================================
__global__ __launch_bounds__(256, 2) void k1_xt_bins_inv(
    const float* __restrict__ x, const int* __restrict__ index,
    const float* __restrict__ Wft, const float* __restrict__ Wm,
    float* __restrict__ ws)
{
  __shared__ __align__(16) float smem[16384];   // 64 KB
  const int blk = blockIdx.x, tid = threadIdx.x;
  if (blk != 0) {
    float* xl = smem;          // [128 c][64 px]
    float* wl = smem + 8192;   // [128 c][64 o]
    const int eb = blk - 1;
    const int b = eb >> 8, ps = eb & 255;
    const float* xg = x + (size_t)b * CIN * HW + ps * 64;
#pragma unroll
    for (int j = 0; j < 8; ++j) {
      const int fj = j * 256 + tid;
      const int c = fj >> 4, q4 = (fj & 15) * 4;
      *(float4*)&xl[c * 64 + q4] = *(const float4*)(xg + (size_t)c * HW + q4);
      *(float4*)&wl[c * 64 + q4] = *(const float4*)(Wft + c * 64 + q4);
    }
    __syncthreads();
    const int px_grp = tid & 15, o_grp = tid >> 4;
    const int px = ps * 64 + px_grp * 4, o0 = o_grp * 4;
    float acc[16];
#pragma unroll
    for (int j = 0; j < 16; ++j) acc[j] = 0.f;
#pragma unroll 8
    for (int c = 0; c < 128; ++c) {
      const float4 xv = *(const float4*)&xl[c * 64 + px_grp * 4];
      const float4 wv = *(const float4*)&wl[c * 64 + o0];
      FMA16();
    }
    unsigned short* xtu = (unsigned short*)(ws + OFF_XT);
#pragma unroll
    for (int oj = 0; oj < 4; ++oj) {
      ushort4 u;
      u.x = f2bfu(acc[oj*4+0]); u.y = f2bfu(acc[oj*4+1]);
      u.z = f2bfu(acc[oj*4+2]); u.w = f2bfu(acc[oj*4+3]);
      *(ushort4*)(xtu + (size_t)(b * 64 + o0 + oj) * HW + px) = u;
    }
    const int4 kv = *(const int4*)(index + b * HW + px);
    const int kk[4] = {kv.x, kv.y, kv.z, kv.w};
    __syncthreads();
    float* bins = smem;
    float* cnt_s = smem + 64 * 68;
    for (int i = tid; i < 64 * 68 + 64; i += 256) smem[i] = 0.f;
    __syncthreads();
#pragma unroll
    for (int pj = 0; pj < 4; ++pj) {
      const int kb = kk[pj] * 68 + o0;
      atomicAdd(&bins[kb    ], acc[ 0 + pj]);
      atomicAdd(&bins[kb + 1], acc[ 4 + pj]);
      atomicAdd(&bins[kb + 2], acc[ 8 + pj]);
      atomicAdd(&bins[kb + 3], acc[12 + pj]);
    }
    if (o_grp == 0) {
#pragma unroll
      for (int pj = 0; pj < 4; ++pj) atomicAdd(&cnt_s[kk[pj]], 1.f);
    }
    __syncthreads();
    unsigned short* pb = (unsigned short*)(ws + OFF_PS) + (size_t)eb * 4096;
    {
      const int k = tid >> 2, ob = (tid & 3) * 16;
#pragma unroll
      for (int q = 0; q < 4; ++q) {
        const float4 v = *(const float4*)&bins[k * 68 + ob + q * 4];
        ushort4 u;
        u.x = f2bfu(v.x); u.y = f2bfu(v.y); u.z = f2bfu(v.z); u.w = f2bfu(v.w);
        *(ushort4*)(pb + k * 64 + ob + q * 4) = u;
      }
    }
    if (tid < 64) ws[OFF_PC + (size_t)(b * 64 + tid) * 256 + ps] = cnt_s[tid];
  } else {
    if (tid == 0) *(unsigned*)(ws + OFF_FLG) = 0u;   // rank counter for K15'
    // inverse block: blocked Gauss-Jordan, 16 panels of 4 pivots (proven form)
    float* wm = smem;
    float* Rb = smem + 8192;
    float* Cb = smem + 8704;
    for (int e = tid; e < 4096; e += 256) wm[(e >> 6) * 68 + (e & 63)] = Wm[e];
    __syncthreads();
    const int ig = tid >> 4, jg = tid & 15;
    const int i0 = ig << 2, j0 = jg << 2;
    float c4[16];
#pragma unroll
    for (int q = 0; q < 16; ++q) c4[q] = 0.f;
    for (int cq = 0; cq < 64; cq += 4) {
      float4 a[4], bb[4];
#pragma unroll
      for (int ii = 0; ii < 4; ++ii) a[ii]  = *(const float4*)&wm[(i0+ii)*68 + cq];
#pragma unroll
      for (int jj = 0; jj < 4; ++jj) bb[jj] = *(const float4*)&wm[(j0+jj)*68 + cq];
#pragma unroll
      for (int ii = 0; ii < 4; ++ii)
#pragma unroll
        for (int jj = 0; jj < 4; ++jj)
          c4[ii*4+jj] = fmaf(a[ii].x, bb[jj].x, fmaf(a[ii].y, bb[jj].y,
                        fmaf(a[ii].z, bb[jj].z, fmaf(a[ii].w, bb[jj].w, c4[ii*4+jj]))));
    }
    __syncthreads();
    __builtin_amdgcn_s_setprio(3);
    int buf = 0;
#pragma unroll 1   // MUST stay rolled (I$ thrash)
    for (int p = 0; p < 16; ++p) {
      const int P = p << 2;
      float* Rp = Rb + buf * 256;
      float* Cp = Cb + buf * 256;
      if (ig == p) {
#pragma unroll
        for (int r = 0; r < 4; ++r) {
          float4 t; t.x = c4[r*4+0]; t.y = c4[r*4+1]; t.z = c4[r*4+2]; t.w = c4[r*4+3];
          *(float4*)&Rp[r * 64 + j0] = t;
        }
      }
      if (jg == p) {
#pragma unroll
        for (int ii = 0; ii < 4; ++ii) {
          float4 t; t.x = c4[ii*4+0]; t.y = c4[ii*4+1]; t.z = c4[ii*4+2]; t.w = c4[ii*4+3];
          *(float4*)&Cp[(i0 + ii) * 4] = t;
        }
      }
      __syncthreads();
      float dd[16], cc[16], rr[16];
#pragma unroll
      for (int r = 0; r < 4; ++r) *(float4*)&dd[r * 4] = *(const float4*)&Rp[r * 64 + P];
#pragma unroll
      for (int ii = 0; ii < 4; ++ii) *(float4*)&cc[ii * 4] = *(const float4*)&Cp[(i0 + ii) * 4];
#pragma unroll
      for (int r = 0; r < 4; ++r) *(float4*)&rr[r * 4] = *(const float4*)&Rp[r * 64 + j0];
#pragma unroll
      for (int k = 0; k < 4; ++k) {
        const float rp = __builtin_amdgcn_rcpf(dd[k * 4 + k]);
        float ai[4], s[4];
#pragma unroll
        for (int j = 0; j < 4; ++j) s[j] = dd[k * 4 + j];
#pragma unroll
        for (int i = 0; i < 4; ++i) ai[i] = (i == k) ? (rp - 1.0f) : (-dd[i * 4 + k] * rp);
#pragma unroll
        for (int i = 0; i < 4; ++i)
#pragma unroll
          for (int j = 0; j < 4; ++j) dd[i * 4 + j] = fmaf(ai[i], s[j], dd[i * 4 + j]);
#pragma unroll
        for (int i = 0; i < 4; ++i) dd[i * 4 + k] = (i == k) ? rp : ai[i];
      }
      float T[16];
#pragma unroll
      for (int ii = 0; ii < 4; ++ii)
#pragma unroll
        for (int c = 0; c < 4; ++c) {
          float t = cc[ii*4+0] * dd[0*4+c];
          t = fmaf(cc[ii*4+1], dd[1*4+c], t);
          t = fmaf(cc[ii*4+2], dd[2*4+c], t);
          t = fmaf(cc[ii*4+3], dd[3*4+c], t);
          T[ii*4+c] = t;
        }
      if (ig == p && jg == p) {
#pragma unroll
        for (int q = 0; q < 16; ++q) c4[q] = dd[q];
      } else if (ig == p) {
#pragma unroll
        for (int r = 0; r < 4; ++r)
#pragma unroll
          for (int jj = 0; jj < 4; ++jj) {
            float t = dd[r*4+0] * rr[0*4+jj];
            t = fmaf(dd[r*4+1], rr[1*4+jj], t);
            t = fmaf(dd[r*4+2], rr[2*4+jj], t);
            t = fmaf(dd[r*4+3], rr[3*4+jj], t);
            c4[r*4+jj] = t;
          }
      } else if (jg == p) {
#pragma unroll
        for (int q = 0; q < 16; ++q) c4[q] = -T[q];
      } else {
#pragma unroll
        for (int ii = 0; ii < 4; ++ii)
#pragma unroll
          for (int jj = 0; jj < 4; ++jj) {
            float t = c4[ii*4+jj];
            t = fmaf(-T[ii*4+0], rr[0*4+jj], t);
            t = fmaf(-T[ii*4+1], rr[1*4+jj], t);
            t = fmaf(-T[ii*4+2], rr[2*4+jj], t);
            t = fmaf(-T[ii*4+3], rr[3*4+jj], t);
            c4[ii*4+jj] = t;
          }
      }
      buf ^= 1;
    }
    __builtin_amdgcn_s_setprio(0);
#pragma unroll
    for (int ii = 0; ii < 4; ++ii)
#pragma unroll
      for (int jj = 0; jj < 4; ++jj)
        ws[OFF_INV + (size_t)(i0 + ii) * 64 + j0 + jj] = c4[ii*4+jj];
  }
}

// ============================================================================
// K15': means (128 blocks x 1024 thr, proven baseline body) + TAIL-RANK adj:
// each block rank-RMWs a counter after its means store; the rank-127 block —
// which by acquire-on-RMW is guaranteed to see ALL means — computes the whole
// adj+adjm for both b itself (~3us, 1024 thr). NO block ever waits.
// ============================================================================
__global__ __launch_bounds__(1024) void k15_means_adjtail(float* __restrict__ ws)
{
  __shared__ __align__(16) float smem[13120];   // 52.5 KB (tail phase is the max)
  __shared__ int rank_s;
  const int blk = blockIdx.x, t = threadIdx.x;
  {
    // ---- means body (baseline k15_means_diag minus diag) ----
    float* red   = smem;           // [16][64]
    float* lds_c = smem + 1024;    // [4]
    const int b = blk >> 6, k = blk & 63;
    const int o = t & 63, chunk = t >> 6;
    const unsigned short* psu = (const unsigned short*)(ws + OFF_PS);
    float s = 0.f;
#pragma unroll
    for (int i = 0; i < 16; ++i) {
      const int slab = chunk * 16 + i;
      s += bf2f(psu[(size_t)(b * 256 + slab) * 4096 + k * 64 + o]);
    }
    red[chunk * 64 + o] = s;
    float cv = 0.f;
    if (t < 256) cv = ws[OFF_PC + (size_t)(b * 64 + k) * 256 + t];
#pragma unroll
    for (int m = 32; m; m >>= 1) cv += __shfl_xor(cv, m, 64);
    if (t < 256 && (t & 63) == 0) lds_c[t >> 6] = cv;
    __syncthreads();
    if (t < 64) {
      float m_raw = 0.f;
#pragma unroll
      for (int ch = 0; ch < 16; ++ch) m_raw += red[ch * 64 + o];
      const float cnt = lds_c[0] + lds_c[1] + lds_c[2] + lds_c[3];
      const float denom = cnt + ((cnt == 0.f) ? 1.f : 0.f);
      ws[OFF_MEANS + (size_t)(b * 64 + k) * 64 + o] = m_raw / denom;
    }
  }
  __syncthreads();   // all waves' means stores drained before the release-RMW
  if (t == 0)
    rank_s = (int)__hip_atomic_fetch_add((unsigned*)(ws + OFF_FLG), 1u,
                                         __ATOMIC_ACQ_REL, __HIP_MEMORY_SCOPE_AGENT);
  __syncthreads();
  if (rank_s != 127) return;   // only the last-arriving block continues

  // ---- tail: full adj + adjm for both b (rank-127 saw all 128 releases) ----
  float* means_s = smem;           // [64][68]
  float* inv_s   = smem + 4352;    // [64][68] (overlaid by adj after T is built)
  float* T_s     = smem + 8704;    // [64][68]
  float* d_s     = smem + 13056;   // [64]
  float* adj_s   = inv_s;          // overlay
  for (int b2 = 0; b2 < 2; ++b2) {
    for (int e = t; e < 4096; e += 1024) {
      means_s[(e >> 6) * 68 + (e & 63)] = ws[OFF_MEANS + (size_t)b2 * 4096 + e];
      inv_s  [(e >> 6) * 68 + (e & 63)] = ws[OFF_INV + e];
    }
    __syncthreads();
    {   // T[j] = means[j] @ inv ; d[j] = T[j].means[j]
      const int j = t >> 4, oq = (t & 15) * 4;
      float4 Ta = {0.f, 0.f, 0.f, 0.f};
      for (int c = 0; c < 64; ++c) {
        const float mv = means_s[j * 68 + c];
        const float4 iv = *(const float4*)&inv_s[c * 68 + oq];
        Ta.x = fmaf(mv, iv.x, Ta.x); Ta.y = fmaf(mv, iv.y, Ta.y);
        Ta.z = fmaf(mv, iv.z, Ta.z); Ta.w = fmaf(mv, iv.w, Ta.w);
      }
      *(float4*)&T_s[j * 68 + oq] = Ta;
      const float4 mvv = *(const float4*)&means_s[j * 68 + oq];
      float dp = Ta.x * mvv.x;
      dp = fmaf(Ta.y, mvv.y, dp); dp = fmaf(Ta.z, mvv.z, dp); dp = fmaf(Ta.w, mvv.w, dp);
      dp += __shfl_xor(dp, 1, 64); dp += __shfl_xor(dp, 2, 64);
      dp += __shfl_xor(dp, 4, 64); dp += __shfl_xor(dp, 8, 64);
      if ((t & 15) == 0) d_s[j] = dp;
    }
    __syncthreads();
    {   // adj[i][j] = exp(-sqrt(max(d_i + d_j - 2 T_i.m_j, 1e-12)))  (overlays inv_s)
      const int i = t >> 4, jb = (t & 15) * 4;
#pragma unroll
      for (int jj = 0; jj < 4; ++jj) {
        const int jc = jb + jj;
        float4 p4 = {0.f, 0.f, 0.f, 0.f};
        for (int dq = 0; dq < 64; dq += 4) {
          const float4 tv = *(const float4*)&T_s[i * 68 + dq];
          const float4 mv = *(const float4*)&means_s[jc * 68 + dq];
          p4.x = fmaf(tv.x, mv.x, p4.x); p4.y = fmaf(tv.y, mv.y, p4.y);
          p4.z = fmaf(tv.z, mv.z, p4.z); p4.w = fmaf(tv.w, mv.w, p4.w);
        }
        const float p = (p4.x + p4.y) + (p4.z + p4.w);
        const float q = d_s[i] + d_s[jc] - 2.f * p;
        adj_s[i * 68 + jc] = __expf(-sqrtf(fmaxf(q, 1e-12f)));
      }
    }
    __syncthreads();
    {   // adjm[i][o] = sum_j adj[i][j] * means[j][o]
      const int i = t >> 4, oq4 = (t & 15) * 4;
      float4 am = {0.f, 0.f, 0.f, 0.f};
      for (int jc = 0; jc < 64; ++jc) {
        const float av = adj_s[i * 68 + jc];
        const float4 mv = *(const float4*)&means_s[jc * 68 + oq4];
        am.x = fmaf(av, mv.x, am.x); am.y = fmaf(av, mv.y, am.y);
        am.z = fmaf(av, mv.z, am.z); am.w = fmaf(av, mv.w, am.w);
      }
      *(float4*)(ws + OFF_ADJM + (size_t)(b2 * 64 + i) * 64 + oq4) = am;
    }
    __syncthreads();   // adj_s/means_s reads done before next-b2 overwrite
  }
}

// ============================================================================
// K3: BN partial stats of f = relu(xt + adj_means[idx]). Verbatim baseline.
// ============================================================================
__global__ __launch_bounds__(256) void k3_bnstats(const int* __restrict__ index,
                                                  float* __restrict__ ws)
{
  __shared__ float am_s[128];
  __shared__ float red[4];
  const int blk = blockIdx.x, t = threadIdx.x;
  const int b = blk >> 8, oc = (blk >> 3) & 31, tile = blk & 7;
  const int o0 = oc * 2;
  if (t < 128) am_s[t] = ws[OFF_ADJM + (size_t)(b * 64 + (t >> 1)) * 64 + o0 + (t & 1)];
  if (t < 4) red[t] = 0.f;
  __syncthreads();
  const int lane = t & 63, w = t >> 6;
  const unsigned short* xtu = (const unsigned short*)(ws + OFF_XT);
  float s0 = 0.f, s1 = 0.f, q0 = 0.f, q1 = 0.f;
#pragma unroll
  for (int q = 0; q < 2; ++q) {
    const int px = tile * 2048 + (w * 2 + q) * 256 + lane * 4;
    const int4 kv = *(const int4*)(index + b * HW + px);
    const ushort4 u0 = *(const ushort4*)(xtu + (size_t)(b * 64 + o0    ) * HW + px);
    const ushort4 u1 = *(const ushort4*)(xtu + (size_t)(b * 64 + o0 + 1) * HW + px);
    const int kk[4] = {kv.x, kv.y, kv.z, kv.w};
    const float x0[4] = {bf2f(u0.x), bf2f(u0.y), bf2f(u0.z), bf2f(u0.w)};
    const float x1[4] = {bf2f(u1.x), bf2f(u1.y), bf2f(u1.z), bf2f(u1.w)};
#pragma unroll
    for (int j = 0; j < 4; ++j) {
      const float2 am = *(const float2*)&am_s[kk[j] * 2];
      const float f0 = fmaxf(x0[j] + am.x, 0.f);
      const float f1 = fmaxf(x1[j] + am.y, 0.f);
      s0 += f0; q0 = fmaf(f0, f0, q0);
      s1 += f1; q1 = fmaf(f1, f1, q1);
    }
  }
#pragma unroll
  for (int m = 1; m < 64; m <<= 1) {
    s0 += __shfl_xor(s0, m, 64); s1 += __shfl_xor(s1, m, 64);
    q0 += __shfl_xor(q0, m, 64); q1 += __shfl_xor(q1, m, 64);
  }
  if (lane == 0) {
    atomicAdd(&red[0], s0); atomicAdd(&red[1], s1);
    atomicAdd(&red[2], q0); atomicAdd(&red[3], q1);
  }
  __syncthreads();
  if (t == 0) {
    float4 v; v.x = red[0]; v.y = red[1]; v.z = red[2]; v.w = red[3];
    *(float4*)(ws + OFF_BNP + (size_t)(oc * 16 + b * 8 + tile) * 4) = v;
  }
}

// ============================================================================
// K4: redundant BN-final reduce per block, then out = f*scale + shift. Verbatim.
// ============================================================================
__global__ __launch_bounds__(256) void k4_out(const int* __restrict__ index,
    const float* __restrict__ gamma, const float* __restrict__ beta,
    const float* __restrict__ ws, float* __restrict__ out)
{
  __shared__ float am_s[128];
  __shared__ float4 tmp[16];
  __shared__ float sc_s[2], sh_s[2];
  const int blk = blockIdx.x, t = threadIdx.x;
  const int b = blk >> 8, oc = (blk >> 3) & 31, tile = blk & 7;
  const int o0 = oc * 2;
  if (t < 128) am_s[t] = ws[OFF_ADJM + (size_t)(b * 64 + (t >> 1)) * 64 + o0 + (t & 1)];
  if (t < 16) tmp[t] = *(const float4*)(ws + OFF_BNP + (size_t)(oc * 16 + t) * 4);
  if (t < 2) {   // same wave as tmp writers: per-wave LDS ordering suffices
    float s = 0.f, qq = 0.f;
#pragma unroll
    for (int i = 0; i < 16; ++i) {
      const float4 v = tmp[i];
      s  += (t == 0) ? v.x : v.y;
      qq += (t == 0) ? v.z : v.w;
    }
    const float mean = s * (1.f / 32768.f);
    const float var  = qq * (1.f / 32768.f) - mean * mean;
    const float sc = gamma[o0 + t] * rsqrtf(var + 1e-5f);
    sc_s[t] = sc;
    sh_s[t] = fmaf(-mean, sc, beta[o0 + t]);
  }
  __syncthreads();
  const int lane = t & 63, w = t >> 6;
  const unsigned short* xtu = (const unsigned short*)(ws + OFF_XT);
  const float c0 = sc_s[0], c1 = sc_s[1], h0 = sh_s[0], h1 = sh_s[1];
#pragma unroll
  for (int q = 0; q < 2; ++q) {
    const int px = tile * 2048 + (w * 2 + q) * 256 + lane * 4;
    const int4 kv = *(const int4*)(index + b * HW + px);
    const ushort4 u0 = *(const ushort4*)(xtu + (size_t)(b * 64 + o0    ) * HW + px);
    const ushort4 u1 = *(const ushort4*)(xtu + (size_t)(b * 64 + o0 + 1) * HW + px);
    const int kk[4] = {kv.x, kv.y, kv.z, kv.w};
    const float x0[4] = {bf2f(u0.x), bf2f(u0.y), bf2f(u0.z), bf2f(u0.w)};
    const float x1[4] = {bf2f(u1.x), bf2f(u1.y), bf2f(u1.z), bf2f(u1.w)};
    float4 o4a, o4b;
    float* oa = (float*)&o4a; float* ob = (float*)&o4b;
#pragma unroll
    for (int j = 0; j < 4; ++j) {
      const float2 am = *(const float2*)&am_s[kk[j] * 2];
      oa[j] = fmaf(fmaxf(x0[j] + am.x, 0.f), c0, h0);
      ob[j] = fmaf(fmaxf(x1[j] + am.y, 0.f), c1, h1);
    }
    *(float4*)(out + (size_t)(b * 64 + o0    ) * HW + px) = o4a;
    *(float4*)(out + (size_t)(b * 64 + o0 + 1) * HW + px) = o4b;
  }
}

extern "C" void kernel_launch(void* const* d_in, const int* in_sizes, int n_in,
                              void* d_out, int out_size, void* d_ws, size_t ws_size,
                              hipStream_t stream) {
  const float* x     = (const float*)d_in[0];
  const int*   index = (const int*)d_in[1];
  const float* Wft   = (const float*)d_in[2];
  const float* Wm    = (const float*)d_in[3];
  const float* gamma = (const float*)d_in[4];
  const float* beta  = (const float*)d_in[5];
  float* ws  = (float*)d_ws;
  float* out = (float*)d_out;

  k1_xt_bins_inv<<<513, 256, 0, stream>>>(x, index, Wft, Wm, ws);
  k15_means_adjtail<<<128, 1024, 0, stream>>>(ws);
  k3_bnstats<<<512, 256, 0, stream>>>(index, ws);
  k4_out<<<512, 256, 0, stream>>>(index, gamma, beta, ws, out);
}

// Round 7
// 121.420 us; speedup vs baseline: 1.6000x; 1.1845x over previous
//
#include <hip/hip_runtime.h>
#include <hip/hip_bf16.h>

// Problem constants
#define CIN   128
#define COUT  64
#define HW    16384   // 128*128

typedef __hip_bfloat16 bf16;

// Workspace layout (float offsets) — proven baseline layout
#define OFF_XT    0u          // bf16[2][64][16384]  xt
#define OFF_PS    1048576u    // bf16[512 blk][64 k][64 o] partial bin sums
#define OFF_PC    2097152u    // f32 [2][64][256]    partial bin counts
#define OFF_MEANS 2129920u    // f32 [2][64][64]
#define OFF_INV   2138240u    // f32 [64][64]        inv(cov)
#define OFF_ADJM  2142336u    // f32 [2][64][64]     adj @ means
#define OFF_BNP   2150528u    // f32 [32 oc][16 b*tile] float4 {s0,s1,ss0,ss1}

__device__ __forceinline__ unsigned short f2bfu(float f) {
  union { bf16 h; unsigned short u; } cv; cv.h = __float2bfloat16(f); return cv.u;
}
__device__ __forceinline__ float bf2f(unsigned short u) {
  union { unsigned int i; float f; } cv; cv.i = ((unsigned int)u) << 16; return cv.f;
}

#define FMA16() do { \
  acc[ 0]=fmaf(xv.x,wv.x,acc[ 0]); acc[ 1]=fmaf(xv.y,wv.x,acc[ 1]); \
  acc[ 2]=fmaf(xv.z,wv.x,acc[ 2]); acc[ 3]=fmaf(xv.w,wv.x,acc[ 3]); \
  acc[ 4]=fmaf(xv.x,wv.y,acc[ 4]); acc[ 5]=fmaf(xv.y,wv.y,acc[ 5]); \
  acc[ 6]=fmaf(xv.z,wv.y,acc[ 6]); acc[ 7]=fmaf(xv.w,wv.y,acc[ 7]); \
  acc[ 8]=fmaf(xv.x,wv.z,acc[ 8]); acc[ 9]=fmaf(xv.y,wv.z,acc[ 9]); \
  acc[10]=fmaf(xv.z,wv.z,acc[10]); acc[11]=fmaf(xv.w,wv.z,acc[11]); \
  acc[12]=fmaf(xv.x,wv.w,acc[12]); acc[13]=fmaf(xv.y,wv.w,acc[13]); \
  acc[14]=fmaf(xv.z,wv.w,acc[14]); acc[15]=fmaf(xv.w,wv.w,acc[15]); \
} while (0)

// ============================================================================
// K1: xt = einsum (bf16 out) + per-block bin partials; block 0 = inv(Wm Wm^T).
// R7-lesson structure, ONE change vs the proven 121us baseline: Wft staged in
// LDS as bf16 (wv ds_read b128->b64; inner loop was LDS-throughput-bound at
// 2xb128 = 24cyc/c vs 32cyc VALU — now 18cyc LDS / 40cyc... both ~overlap).
// x stays f32 (W-rounding adds xt error ~0.001, << existing bf16-xt storage).
// ============================================================================
__global__ __launch_bounds__(256, 2) void k1_xt_bins_inv(
    const float* __restrict__ x, const int* __restrict__ index,
    const float* __restrict__ Wft, const float* __restrict__ Wm,
    float* __restrict__ ws)
{
  __shared__ __align__(16) float smem[16384];   // 64 KB (occupancy same as proven)
  const int blk = blockIdx.x, tid = threadIdx.x;
  if (blk != 0) {
    float* xl = smem;                               // f32 [128 c][64 px] (32 KB)
    unsigned short* wlb = (unsigned short*)(smem + 8192);   // bf16 [128 c][64 o] (16 KB)
    const int eb = blk - 1;
    const int b = eb >> 8, ps = eb & 255;
    const float* xg = x + (size_t)b * CIN * HW + ps * 64;
#pragma unroll
    for (int j = 0; j < 8; ++j) {
      const int fj = j * 256 + tid;
      const int c = fj >> 4, q4 = (fj & 15) * 4;
      *(float4*)&xl[c * 64 + q4] = *(const float4*)(xg + (size_t)c * HW + q4);
      const float4 wv4 = *(const float4*)(Wft + c * 64 + q4);
      ushort4 wu;
      wu.x = f2bfu(wv4.x); wu.y = f2bfu(wv4.y);
      wu.z = f2bfu(wv4.z); wu.w = f2bfu(wv4.w);
      *(ushort4*)&wlb[c * 64 + q4] = wu;
    }
    __syncthreads();
    const int px_grp = tid & 15, o_grp = tid >> 4;
    const int px = ps * 64 + px_grp * 4, o0 = o_grp * 4;
    float acc[16];
#pragma unroll
    for (int j = 0; j < 16; ++j) acc[j] = 0.f;
#pragma unroll 8
    for (int c = 0; c < 128; ++c) {
      const float4 xv = *(const float4*)&xl[c * 64 + px_grp * 4];
      const ushort4 wu = *(const ushort4*)&wlb[c * 64 + o0];
      float4 wv;
      wv.x = bf2f(wu.x); wv.y = bf2f(wu.y); wv.z = bf2f(wu.z); wv.w = bf2f(wu.w);
      FMA16();
    }
    unsigned short* xtu = (unsigned short*)(ws + OFF_XT);
#pragma unroll
    for (int oj = 0; oj < 4; ++oj) {
      ushort4 u;
      u.x = f2bfu(acc[oj*4+0]); u.y = f2bfu(acc[oj*4+1]);
      u.z = f2bfu(acc[oj*4+2]); u.w = f2bfu(acc[oj*4+3]);
      *(ushort4*)(xtu + (size_t)(b * 64 + o0 + oj) * HW + px) = u;
    }
    const int4 kv = *(const int4*)(index + b * HW + px);
    const int kk[4] = {kv.x, kv.y, kv.z, kv.w};
    __syncthreads();
    float* bins = smem;                    // [64 k][68] padded
    float* cnt_s = smem + 64 * 68;         // [64]
    for (int i = tid; i < 64 * 68 + 64; i += 256) smem[i] = 0.f;
    __syncthreads();
#pragma unroll
    for (int pj = 0; pj < 4; ++pj) {
      const int kb = kk[pj] * 68 + o0;
      atomicAdd(&bins[kb    ], acc[ 0 + pj]);
      atomicAdd(&bins[kb + 1], acc[ 4 + pj]);
      atomicAdd(&bins[kb + 2], acc[ 8 + pj]);
      atomicAdd(&bins[kb + 3], acc[12 + pj]);
    }
    if (o_grp == 0) {   // exactly one thread per px
#pragma unroll
      for (int pj = 0; pj < 4; ++pj) atomicAdd(&cnt_s[kk[pj]], 1.f);
    }
    __syncthreads();
    unsigned short* pb = (unsigned short*)(ws + OFF_PS) + (size_t)eb * 4096;
    {
      const int k = tid >> 2, ob = (tid & 3) * 16;
#pragma unroll
      for (int q = 0; q < 4; ++q) {
        const float4 v = *(const float4*)&bins[k * 68 + ob + q * 4];
        ushort4 u;
        u.x = f2bfu(v.x); u.y = f2bfu(v.y); u.z = f2bfu(v.z); u.w = f2bfu(v.w);
        *(ushort4*)(pb + k * 64 + ob + q * 4) = u;
      }
    }
    if (tid < 64) ws[OFF_PC + (size_t)(b * 64 + tid) * 256 + ps] = cnt_s[tid];
  } else {
    // inverse block: blocked Gauss-Jordan, 16 panels of 4 pivots (proven form)
    float* wm = smem;
    float* Rb = smem + 8192;
    float* Cb = smem + 8704;
    for (int e = tid; e < 4096; e += 256) wm[(e >> 6) * 68 + (e & 63)] = Wm[e];
    __syncthreads();
    const int ig = tid >> 4, jg = tid & 15;
    const int i0 = ig << 2, j0 = jg << 2;
    float c4[16];
#pragma unroll
    for (int q = 0; q < 16; ++q) c4[q] = 0.f;
    for (int cq = 0; cq < 64; cq += 4) {
      float4 a[4], bb[4];
#pragma unroll
      for (int ii = 0; ii < 4; ++ii) a[ii]  = *(const float4*)&wm[(i0+ii)*68 + cq];
#pragma unroll
      for (int jj = 0; jj < 4; ++jj) bb[jj] = *(const float4*)&wm[(j0+jj)*68 + cq];
#pragma unroll
      for (int ii = 0; ii < 4; ++ii)
#pragma unroll
        for (int jj = 0; jj < 4; ++jj)
          c4[ii*4+jj] = fmaf(a[ii].x, bb[jj].x, fmaf(a[ii].y, bb[jj].y,
                        fmaf(a[ii].z, bb[jj].z, fmaf(a[ii].w, bb[jj].w, c4[ii*4+jj]))));
    }
    __syncthreads();
    __builtin_amdgcn_s_setprio(3);
    int buf = 0;
#pragma unroll 1   // MUST stay rolled (I$ thrash)
    for (int p = 0; p < 16; ++p) {
      const int P = p << 2;
      float* Rp = Rb + buf * 256;
      float* Cp = Cb + buf * 256;
      if (ig == p) {
#pragma unroll
        for (int r = 0; r < 4; ++r) {
          float4 t; t.x = c4[r*4+0]; t.y = c4[r*4+1]; t.z = c4[r*4+2]; t.w = c4[r*4+3];
          *(float4*)&Rp[r * 64 + j0] = t;
        }
      }
      if (jg == p) {
#pragma unroll
        for (int ii = 0; ii < 4; ++ii) {
          float4 t; t.x = c4[ii*4+0]; t.y = c4[ii*4+1]; t.z = c4[ii*4+2]; t.w = c4[ii*4+3];
          *(float4*)&Cp[(i0 + ii) * 4] = t;
        }
      }
      __syncthreads();
      float dd[16], cc[16], rr[16];
#pragma unroll
      for (int r = 0; r < 4; ++r) *(float4*)&dd[r * 4] = *(const float4*)&Rp[r * 64 + P];
#pragma unroll
      for (int ii = 0; ii < 4; ++ii) *(float4*)&cc[ii * 4] = *(const float4*)&Cp[(i0 + ii) * 4];
#pragma unroll
      for (int r = 0; r < 4; ++r) *(float4*)&rr[r * 4] = *(const float4*)&Rp[r * 64 + j0];
#pragma unroll
      for (int k = 0; k < 4; ++k) {
        const float rp = __builtin_amdgcn_rcpf(dd[k * 4 + k]);
        float ai[4], s[4];
#pragma unroll
        for (int j = 0; j < 4; ++j) s[j] = dd[k * 4 + j];
#pragma unroll
        for (int i = 0; i < 4; ++i) ai[i] = (i == k) ? (rp - 1.0f) : (-dd[i * 4 + k] * rp);
#pragma unroll
        for (int i = 0; i < 4; ++i)
#pragma unroll
          for (int j = 0; j < 4; ++j) dd[i * 4 + j] = fmaf(ai[i], s[j], dd[i * 4 + j]);
#pragma unroll
        for (int i = 0; i < 4; ++i) dd[i * 4 + k] = (i == k) ? rp : ai[i];
      }
      float T[16];
#pragma unroll
      for (int ii = 0; ii < 4; ++ii)
#pragma unroll
        for (int c = 0; c < 4; ++c) {
          float t = cc[ii*4+0] * dd[0*4+c];
          t = fmaf(cc[ii*4+1], dd[1*4+c], t);
          t = fmaf(cc[ii*4+2], dd[2*4+c], t);
          t = fmaf(cc[ii*4+3], dd[3*4+c], t);
          T[ii*4+c] = t;
        }
      if (ig == p && jg == p) {
#pragma unroll
        for (int q = 0; q < 16; ++q) c4[q] = dd[q];
      } else if (ig == p) {
#pragma unroll
        for (int r = 0; r < 4; ++r)
#pragma unroll
          for (int jj = 0; jj < 4; ++jj) {
            float t = dd[r*4+0] * rr[0*4+jj];
            t = fmaf(dd[r*4+1], rr[1*4+jj], t);
            t = fmaf(dd[r*4+2], rr[2*4+jj], t);
            t = fmaf(dd[r*4+3], rr[3*4+jj], t);
            c4[r*4+jj] = t;
          }
      } else if (jg == p) {
#pragma unroll
        for (int q = 0; q < 16; ++q) c4[q] = -T[q];
      } else {
#pragma unroll
        for (int ii = 0; ii < 4; ++ii)
#pragma unroll
          for (int jj = 0; jj < 4; ++jj) {
            float t = c4[ii*4+jj];
            t = fmaf(-T[ii*4+0], rr[0*4+jj], t);
            t = fmaf(-T[ii*4+1], rr[1*4+jj], t);
            t = fmaf(-T[ii*4+2], rr[2*4+jj], t);
            t = fmaf(-T[ii*4+3], rr[3*4+jj], t);
            c4[ii*4+jj] = t;
          }
      }
      buf ^= 1;
    }
    __builtin_amdgcn_s_setprio(0);
#pragma unroll
    for (int ii = 0; ii < 4; ++ii)
#pragma unroll
      for (int jj = 0; jj < 4; ++jj)
        ws[OFF_INV + (size_t)(i0 + ii) * 64 + j0 + jj] = c4[ii*4+jj];
  }
}

// ============================================================================
// K15: reduce bin partials -> means. 128 blocks x 1024 thr. Proven baseline
// body with the diag pass REMOVED (K2 computes d internally — R4/R5-proven).
// ============================================================================
__global__ __launch_bounds__(1024) void k15_means(float* __restrict__ ws)
{
  __shared__ float red[1024];
  __shared__ float lds_c[4];
  const int blk = blockIdx.x, t = threadIdx.x;
  const int b = blk >> 6, k = blk & 63;
  const int o = t & 63, chunk = t >> 6;
  const unsigned short* psu = (const unsigned short*)(ws + OFF_PS);
  float s = 0.f;
#pragma unroll
  for (int i = 0; i < 16; ++i) {
    const int slab = chunk * 16 + i;
    s += bf2f(psu[(size_t)(b * 256 + slab) * 4096 + k * 64 + o]);
  }
  red[chunk * 64 + o] = s;
  float cv = 0.f;
  if (t < 256) cv = ws[OFF_PC + (size_t)(b * 64 + k) * 256 + t];
#pragma unroll
  for (int m = 32; m; m >>= 1) cv += __shfl_xor(cv, m, 64);
  if (t < 256 && (t & 63) == 0) lds_c[t >> 6] = cv;
  __syncthreads();
  if (t < 64) {
    float m_raw = 0.f;
#pragma unroll
    for (int ch = 0; ch < 16; ++ch) m_raw += red[ch * 64 + o];
    const float cnt = lds_c[0] + lds_c[1] + lds_c[2] + lds_c[3];
    const float denom = cnt + ((cnt == 0.f) ? 1.f : 0.f);
    ws[OFF_MEANS + (size_t)(b * 64 + k) * 64 + o] = m_raw / denom;
  }
}

// ============================================================================
// K2: adj + adjm. 16 blocks x 256 thr — the R4/R5-proven body (computes T, d_s
// internally from means+inv; no DIAG dependency).
// ============================================================================
__global__ __launch_bounds__(256) void k2_adj(float* __restrict__ ws)
{
  __shared__ __align__(16) float smem[9856];   // 39.4 KB
  const int blk = blockIdx.x, tid = threadIdx.x;
  const int bb = blk >> 3, r0 = (blk & 7) << 3;
  float* means_s = smem;            // [64][68]
  float* inv_s   = smem + 4352;     // [64][68]
  float* T_s     = smem + 8704;     // [8][68]
  float* adj_s   = smem + 9248;     // [8][68]
  float* d_s     = smem + 9792;     // [64]
  const float* mg = ws + OFF_MEANS + (size_t)bb * 4096;
  for (int e = tid; e < 4096; e += 256) means_s[(e >> 6) * 68 + (e & 63)] = mg[e];
  for (int e = tid; e < 4096; e += 256) inv_s[(e >> 6) * 68 + (e & 63)] = ws[OFF_INV + e];
  __syncthreads();
  {   // thread = (row j, 16-col strip): T[j][oq..oq+15], d_j partial
    const int j = tid >> 2, oq = (tid & 3) << 4;
    float4 Ta[4];
#pragma unroll
    for (int v = 0; v < 4; ++v) { Ta[v].x = 0.f; Ta[v].y = 0.f; Ta[v].z = 0.f; Ta[v].w = 0.f; }
    for (int c = 0; c < 64; ++c) {
      const float mv = means_s[j * 68 + c];
#pragma unroll
      for (int v = 0; v < 4; ++v) {
        const float4 iv = *(const float4*)&inv_s[c * 68 + oq + v * 4];
        Ta[v].x = fmaf(mv, iv.x, Ta[v].x); Ta[v].y = fmaf(mv, iv.y, Ta[v].y);
        Ta[v].z = fmaf(mv, iv.z, Ta[v].z); Ta[v].w = fmaf(mv, iv.w, Ta[v].w);
      }
    }
    float dp = 0.f;
#pragma unroll
    for (int v = 0; v < 4; ++v) {
      const float4 mvv = *(const float4*)&means_s[j * 68 + oq + v * 4];
      dp = fmaf(Ta[v].x, mvv.x, dp); dp = fmaf(Ta[v].y, mvv.y, dp);
      dp = fmaf(Ta[v].z, mvv.z, dp); dp = fmaf(Ta[v].w, mvv.w, dp);
    }
    dp += __shfl_xor(dp, 1, 64);
    dp += __shfl_xor(dp, 2, 64);
    if ((tid & 3) == 0) d_s[j] = dp;
    if (j >= r0 && j < r0 + 8) {
#pragma unroll
      for (int v = 0; v < 4; ++v) *(float4*)&T_s[(j - r0) * 68 + oq + v * 4] = Ta[v];
    }
  }
  __syncthreads();
  {   // q_ij = d_i + d_j - 2 T_i.m_j ; adj = exp(-sqrt(max(q,1e-12)))
    const int i = tid >> 5, jb = tid & 31;
#pragma unroll
    for (int jj = 0; jj < 2; ++jj) {
      const int jc = jb + (jj << 5);
      float4 p4 = {0.f, 0.f, 0.f, 0.f};
      for (int dq = 0; dq < 64; dq += 4) {
        const float4 tv = *(const float4*)&T_s[i * 68 + dq];
        const float4 mv = *(const float4*)&means_s[jc * 68 + dq];
        p4.x = fmaf(tv.x, mv.x, p4.x); p4.y = fmaf(tv.y, mv.y, p4.y);
        p4.z = fmaf(tv.z, mv.z, p4.z); p4.w = fmaf(tv.w, mv.w, p4.w);
      }
      const float p = (p4.x + p4.y) + (p4.z + p4.w);
      const float q = d_s[r0 + i] + d_s[jc] - 2.f * p;
      adj_s[i * 68 + jc] = __expf(-sqrtf(fmaxf(q, 1e-12f)));
    }
  }
  __syncthreads();
  if (tid < 128) {   // adjm rows
    const int i = tid >> 4, oq4 = (tid & 15) << 2;
    float4 am = {0.f, 0.f, 0.f, 0.f};
    for (int jc = 0; jc < 64; ++jc) {
      const float av = adj_s[i * 68 + jc];
      const float4 mv = *(const float4*)&means_s[jc * 68 + oq4];
      am.x = fmaf(av, mv.x, am.x); am.y = fmaf(av, mv.y, am.y);
      am.z = fmaf(av, mv.z, am.z); am.w = fmaf(av, mv.w, am.w);
    }
    *(float4*)(ws + OFF_ADJM + (size_t)(bb * 64 + r0 + i) * 64 + oq4) = am;
  }
}

// ============================================================================
// K3: BN partial stats of f = relu(xt + adj_means[idx]). Verbatim baseline.
// ============================================================================
__global__ __launch_bounds__(256) void k3_bnstats(const int* __restrict__ index,
                                                  float* __restrict__ ws)
{
  __shared__ float am_s[128];
  __shared__ float red[4];
  const int blk = blockIdx.x, t = threadIdx.x;
  const int b = blk >> 8, oc = (blk >> 3) & 31, tile = blk & 7;
  const int o0 = oc * 2;
  if (t < 128) am_s[t] = ws[OFF_ADJM + (size_t)(b * 64 + (t >> 1)) * 64 + o0 + (t & 1)];
  if (t < 4) red[t] = 0.f;
  __syncthreads();
  const int lane = t & 63, w = t >> 6;
  const unsigned short* xtu = (const unsigned short*)(ws + OFF_XT);
  float s0 = 0.f, s1 = 0.f, q0 = 0.f, q1 = 0.f;
#pragma unroll
  for (int q = 0; q < 2; ++q) {
    const int px = tile * 2048 + (w * 2 + q) * 256 + lane * 4;
    const int4 kv = *(const int4*)(index + b * HW + px);
    const ushort4 u0 = *(const ushort4*)(xtu + (size_t)(b * 64 + o0    ) * HW + px);
    const ushort4 u1 = *(const ushort4*)(xtu + (size_t)(b * 64 + o0 + 1) * HW + px);
    const int kk[4] = {kv.x, kv.y, kv.z, kv.w};
    const float x0[4] = {bf2f(u0.x), bf2f(u0.y), bf2f(u0.z), bf2f(u0.w)};
    const float x1[4] = {bf2f(u1.x), bf2f(u1.y), bf2f(u1.z), bf2f(u1.w)};
#pragma unroll
    for (int j = 0; j < 4; ++j) {
      const float2 am = *(const float2*)&am_s[kk[j] * 2];
      const float f0 = fmaxf(x0[j] + am.x, 0.f);
      const float f1 = fmaxf(x1[j] + am.y, 0.f);
      s0 += f0; q0 = fmaf(f0, f0, q0);
      s1 += f1; q1 = fmaf(f1, f1, q1);
    }
  }
#pragma unroll
  for (int m = 1; m < 64; m <<= 1) {
    s0 += __shfl_xor(s0, m, 64); s1 += __shfl_xor(s1, m, 64);
    q0 += __shfl_xor(q0, m, 64); q1 += __shfl_xor(q1, m, 64);
  }
  if (lane == 0) {
    atomicAdd(&red[0], s0); atomicAdd(&red[1], s1);
    atomicAdd(&red[2], q0); atomicAdd(&red[3], q1);
  }
  __syncthreads();
  if (t == 0) {
    float4 v; v.x = red[0]; v.y = red[1]; v.z = red[2]; v.w = red[3];
    *(float4*)(ws + OFF_BNP + (size_t)(oc * 16 + b * 8 + tile) * 4) = v;
  }
}

// ============================================================================
// K4: redundant BN-final reduce per block, then out = f*scale + shift. Verbatim.
// ============================================================================
__global__ __launch_bounds__(256) void k4_out(const int* __restrict__ index,
    const float* __restrict__ gamma, const float* __restrict__ beta,
    const float* __restrict__ ws, float* __restrict__ out)
{
  __shared__ float am_s[128];
  __shared__ float4 tmp[16];
  __shared__ float sc_s[2], sh_s[2];
  const int blk = blockIdx.x, t = threadIdx.x;
  const int b = blk >> 8, oc = (blk >> 3) & 31, tile = blk & 7;
  const int o0 = oc * 2;
  if (t < 128) am_s[t] = ws[OFF_ADJM + (size_t)(b * 64 + (t >> 1)) * 64 + o0 + (t & 1)];
  if (t < 16) tmp[t] = *(const float4*)(ws + OFF_BNP + (size_t)(oc * 16 + t) * 4);
  if (t < 2) {   // same wave as tmp writers: per-wave LDS ordering suffices
    float s = 0.f, qq = 0.f;
#pragma unroll
    for (int i = 0; i < 16; ++i) {
      const float4 v = tmp[i];
      s  += (t == 0) ? v.x : v.y;
      qq += (t == 0) ? v.z : v.w;
    }
    const float mean = s * (1.f / 32768.f);
    const float var  = qq * (1.f / 32768.f) - mean * mean;
    const float sc = gamma[o0 + t] * rsqrtf(var + 1e-5f);
    sc_s[t] = sc;
    sh_s[t] = fmaf(-mean, sc, beta[o0 + t]);
  }
  __syncthreads();
  const int lane = t & 63, w = t >> 6;
  const unsigned short* xtu = (const unsigned short*)(ws + OFF_XT);
  const float c0 = sc_s[0], c1 = sc_s[1], h0 = sh_s[0], h1 = sh_s[1];
#pragma unroll
  for (int q = 0; q < 2; ++q) {
    const int px = tile * 2048 + (w * 2 + q) * 256 + lane * 4;
    const int4 kv = *(const int4*)(index + b * HW + px);
    const ushort4 u0 = *(const ushort4*)(xtu + (size_t)(b * 64 + o0    ) * HW + px);
    const ushort4 u1 = *(const ushort4*)(xtu + (size_t)(b * 64 + o0 + 1) * HW + px);
    const int kk[4] = {kv.x, kv.y, kv.z, kv.w};
    const float x0[4] = {bf2f(u0.x), bf2f(u0.y), bf2f(u0.z), bf2f(u0.w)};
    const float x1[4] = {bf2f(u1.x), bf2f(u1.y), bf2f(u1.z), bf2f(u1.w)};
    float4 o4a, o4b;
    float* oa = (float*)&o4a; float* ob = (float*)&o4b;
#pragma unroll
    for (int j = 0; j < 4; ++j) {
      const float2 am = *(const float2*)&am_s[kk[j] * 2];
      oa[j] = fmaf(fmaxf(x0[j] + am.x, 0.f), c0, h0);
      ob[j] = fmaf(fmaxf(x1[j] + am.y, 0.f), c1, h1);
    }
    *(float4*)(out + (size_t)(b * 64 + o0    ) * HW + px) = o4a;
    *(float4*)(out + (size_t)(b * 64 + o0 + 1) * HW + px) = o4b;
  }
}

extern "C" void kernel_launch(void* const* d_in, const int* in_sizes, int n_in,
                              void* d_out, int out_size, void* d_ws, size_t ws_size,
                              hipStream_t stream) {
  const float* x     = (const float*)d_in[0];
  const int*   index = (const int*)d_in[1];
  const float* Wft   = (const float*)d_in[2];
  const float* Wm    = (const float*)d_in[3];
  const float* gamma = (const float*)d_in[4];
  const float* beta  = (const float*)d_in[5];
  float* ws  = (float*)d_ws;
  float* out = (float*)d_out;

  k1_xt_bins_inv<<<513, 256, 0, stream>>>(x, index, Wft, Wm, ws);
  k15_means<<<128, 1024, 0, stream>>>(ws);
  k2_adj<<<16, 256, 0, stream>>>(ws);
  k3_bnstats<<<512, 256, 0, stream>>>(index, ws);
  k4_out<<<512, 256, 0, stream>>>(index, gamma, beta, ws, out);
}